// Round 7
// baseline (1114.143 us; speedup 1.0000x reference)
//
#include <hip/hip_runtime.h>

// ---------------- problem constants ----------------
#define BB 4
#define TT 24
#define NN 2048
#define DD 128
#define HH 4
#define HD 32
#define TOK 196608          // BB*TT*NN
#define EE 8
#define MINTER 256
#define INTER 512

typedef unsigned short u16;
typedef __attribute__((ext_vector_type(8))) short  bf16x8;
typedef __attribute__((ext_vector_type(4))) float  f32x4;
typedef __attribute__((ext_vector_type(4))) unsigned int u32x4;

#define MFMA(a,b,c) __builtin_amdgcn_mfma_f32_16x16x32_bf16((a),(b),(c),0,0,0)
#define AS(n) __attribute__((address_space(n)))

// ---------------- small helpers ----------------
static __device__ __forceinline__ u16 f2b(float f) {
    union { float f; unsigned u; } v; v.f = f;
    unsigned r = v.u + 0x7FFFu + ((v.u >> 16) & 1u);
    return (u16)(r >> 16);
}
static __device__ __forceinline__ float b2f(u16 b) {
    union { unsigned u; float f; } v; v.u = ((unsigned)b) << 16;
    return v.f;
}
static __device__ __forceinline__ float silu_mul(float u, float v) {
    return u * __builtin_amdgcn_rcpf(1.f + __expf(-u)) * v;
}

// LDS tile helpers.  Tiles are [rows][C] bf16, row stride C*2 bytes, with a
// 16B-chunk XOR swizzle: chunk cc of row r lives at byte r*C*2 + ((cc*16) ^ ((r&mask)<<4)).
template<int C>
static __device__ __forceinline__ bf16x8 frag_ld(const u16* s, int row, int kbyte) {
    constexpr int mask = ((C/8) < 8 ? (C/8) : 8) - 1;
    int byte = row * (C * 2) + (kbyte ^ ((row & mask) << 4));
    return *(const bf16x8*)((const char*)s + byte);
}
template<int C>
static __device__ __forceinline__ u16 lds_us(const u16* s, int r, int c) {
    constexpr int mask = ((C/8) < 8 ? (C/8) : 8) - 1;
    int byte = r * (C * 2) + ((((c >> 3) << 4) ^ ((r & mask) << 4))) + ((c & 7) << 1);
    return *(const u16*)((const char*)s + byte);
}
template<int C>
static __device__ __forceinline__ void lds_store_us(u16* s, int r, int c, u16 v) {
    constexpr int mask = ((C/8) < 8 ? (C/8) : 8) - 1;
    int byte = r * (C * 2) + ((((c >> 3) << 4) ^ ((r & mask) << 4))) + ((c & 7) << 1);
    *(u16*)((char*)s + byte) = v;
}
// 80B-padded row stride (period-8 bank pattern, conflict-free for 16B reads)
static __device__ __forceinline__ bf16x8 frag_ld_p80(const u16* s, int row, int kbyte) {
    return *(const bf16x8*)((const char*)s + row * 80 + kbyte);
}
static __device__ __forceinline__ void sh_store_p80(u16* s, int r, int c, u16 v) {
    *(u16*)((char*)s + r * 80 + c * 2) = v;
}
// stage bf16 global -> swizzled LDS tile (reg path)
template<int C>
static __device__ __forceinline__ void stage_bf16(u16* s, const u16* g, int gstride,
                                                  int rows, int tid, int nthr) {
    constexpr int cpr = C / 8;
    constexpr int mask = (cpr < 8 ? cpr : 8) - 1;
    for (int i = tid; i < rows * cpr; i += nthr) {
        int r = i / cpr, cc = i - r * cpr;
        u32x4 v = *(const u32x4*)(g + (size_t)r * gstride + cc * 8);
        *(u32x4*)((char*)s + r * (C * 2) + ((cc * 16) ^ ((r & mask) << 4))) = v;
    }
}
// async stage for a [128][64] bf16 tile from row-major global (stride 2048):
// LDS linear dest (wave base + lane*16), PRE-SWIZZLED global source chunk.
static __device__ __forceinline__ void stage_async64(u16* s, const u16* g, int wi, int lane) {
    int slot = wi * 64 + lane;            // 16B-chunk index in [0,1024)
    int r = slot >> 3, c = slot & 7;
    const u16* src = g + r * 2048 + ((c ^ (r & 7)) << 3);
    __builtin_amdgcn_global_load_lds((const AS(1) void*)src,
                                     (AS(3) void*)(s + wi * 512), 16, 0, 0);
}
static __device__ __forceinline__ void zero_acc(f32x4 acc[4][4]) {
    f32x4 z = {0.f, 0.f, 0.f, 0.f};
    #pragma unroll
    for (int i = 0; i < 4; ++i)
        #pragma unroll
        for (int j = 0; j < 4; ++j) acc[i][j] = z;
}
// one K-step (32) of a 64x64 wave tile: 4 A frags x 4 B frags -> 16 MFMA
template<int CA, int CB>
static __device__ __forceinline__ void gemm_step64(const u16* sA, const u16* sB,
        int arow0, int brow0, int kbyte, f32x4 acc[4][4], int ln15) {
    bf16x8 a[4], b[4];
    #pragma unroll
    for (int i = 0; i < 4; ++i) a[i] = frag_ld<CA>(sA, arow0 + i * 16 + ln15, kbyte);
    #pragma unroll
    for (int j = 0; j < 4; ++j) b[j] = frag_ld<CB>(sB, brow0 + j * 16 + ln15, kbyte);
    #pragma unroll
    for (int i = 0; i < 4; ++i)
        #pragma unroll
        for (int j = 0; j < 4; ++j)
            acc[i][j] = MFMA(a[i], b[j], acc[i][j]);
}

// ---- MoE weight-chunk prefetch (T14 issue-early / write-late) ----
// LDS chunk layout (bytes): W1c [32][128] swz @0 (8KB), W3c swz @8192 (8KB),
// W2c [128] rows @16384 with 80B padded stride (10240B). Total 26624B.
static __device__ __forceinline__ void prefetch_regs(u32x4 pf[6],
        const u16* __restrict__ w1b, const u16* __restrict__ w3b,
        const u16* __restrict__ w2b, int w2s, int tid) {
    #pragma unroll
    for (int p = 0; p < 6; ++p) {
        int i = p * 256 + tid;
        const u16* src;
        if (i < 512)       { int r = i >> 4, cc = i & 15; src = w1b + r * 128 + cc * 8; }
        else if (i < 1024) { int j = i - 512; int r = j >> 4, cc = j & 15; src = w3b + r * 128 + cc * 8; }
        else               { int j = i - 1024; int r = j >> 2, cc = j & 3; src = w2b + (size_t)r * w2s + cc * 8; }
        pf[p] = *(const u32x4*)src;
    }
}
static __device__ __forceinline__ void write_chunk(u16* buf, const u32x4 pf[6], int tid) {
    #pragma unroll
    for (int p = 0; p < 6; ++p) {
        int i = p * 256 + tid;
        char* dst;
        if (i < 512)       { int r = i >> 4, cc = i & 15; dst = (char*)buf + r * 256 + ((cc * 16) ^ ((r & 7) << 4)); }
        else if (i < 1024) { int j = i - 512; int r = j >> 4, cc = j & 15; dst = (char*)buf + 8192 + r * 256 + ((cc * 16) ^ ((r & 7) << 4)); }
        else               { int j = i - 1024; int r = j >> 2, cc = j & 3; dst = (char*)buf + 16384 + r * 80 + cc * 16; }
        *(u32x4*)dst = pf[p];
    }
}
// one swiglu inter-chunk (32 wide): p1 (W1,W3) -> silu -> sH -> p2 accumulate into aout
static __device__ __forceinline__ void swiglu_chunk(const u16* buf, u16* sH,
        const bf16x8 av[2][4], f32x4 aout[2][8],
        int wid, int g16, int ln15) {
    const u16* W1c = buf;
    const u16* W3c = buf + 4096;
    const u16* W2c = buf + 8192;        // 80B-padded rows
    f32x4 z = {0.f, 0.f, 0.f, 0.f};
    f32x4 a1[2][2], a3[2][2];
    #pragma unroll
    for (int mf = 0; mf < 2; ++mf)
        #pragma unroll
        for (int nf = 0; nf < 2; ++nf) { a1[mf][nf] = z; a3[mf][nf] = z; }
    #pragma unroll
    for (int ks = 0; ks < 4; ++ks) {
        int kb = ks * 64 + g16 * 16;
        #pragma unroll
        for (int nf = 0; nf < 2; ++nf) {
            bf16x8 b1 = frag_ld<128>(W1c, nf * 16 + ln15, kb);
            bf16x8 b3 = frag_ld<128>(W3c, nf * 16 + ln15, kb);
            a1[0][nf] = MFMA(av[0][ks], b1, a1[0][nf]);
            a1[1][nf] = MFMA(av[1][ks], b1, a1[1][nf]);
            a3[0][nf] = MFMA(av[0][ks], b3, a3[0][nf]);
            a3[1][nf] = MFMA(av[1][ks], b3, a3[1][nf]);
        }
    }
    #pragma unroll
    for (int mf = 0; mf < 2; ++mf)
        #pragma unroll
        for (int nf = 0; nf < 2; ++nf)
            #pragma unroll
            for (int r = 0; r < 4; ++r) {
                int row = wid * 32 + mf * 16 + g16 * 4 + r;
                int col = nf * 16 + ln15;
                sh_store_p80(sH, row, col, f2b(silu_mul(a1[mf][nf][r], a3[mf][nf][r])));
            }
    // sH rows are wave-private: wave w writes & reads only rows w*32..w*32+31
    asm volatile("s_waitcnt lgkmcnt(0)" ::: "memory");
    __builtin_amdgcn_sched_barrier(0);
    {
        int kb = g16 * 16;
        bf16x8 ah0 = frag_ld_p80(sH, wid * 32 + ln15, kb);
        bf16x8 ah1 = frag_ld_p80(sH, wid * 32 + 16 + ln15, kb);
        #pragma unroll
        for (int nf = 0; nf < 8; ++nf) {
            bf16x8 bw = frag_ld_p80(W2c, nf * 16 + ln15, kb);
            aout[0][nf] = MFMA(ah0, bw, aout[0][nf]);
            aout[1][nf] = MFMA(ah1, bw, aout[1][nf]);
        }
    }
}

// ---------------- K0: preconvert all weight matrices f32 -> bf16 arena; zero cnts ----------------
__global__ __launch_bounds__(256) void preconvert(
        const float* __restrict__ Wq, const float* __restrict__ Wk,
        const float* __restrict__ Wv, const float* __restrict__ g1,
        const float* __restrict__ g2,
        const float* __restrict__ e1, const float* __restrict__ e2,
        const float* __restrict__ e3,
        const float* __restrict__ s1, const float* __restrict__ s2,
        const float* __restrict__ s3,
        u16* __restrict__ arena, int* __restrict__ cnts) {
    int idx = blockIdx.x * 256 + threadIdx.x;
    if (blockIdx.x == 0 && threadIdx.x < 8) cnts[threadIdx.x] = 0;
    if (idx >= 266240) return;
    const float* src; int rel;
    if (idx < 20480) {
        int s = idx >> 12; rel = idx & 4095;
        src = (s == 0) ? Wq : (s == 1) ? Wk : (s == 2) ? Wv : (s == 3) ? g1 : g2;
    } else if (idx < 217088) {
        int t = idx - 20480; int s = t >> 16; rel = t & 65535;
        src = (s == 0) ? e1 : (s == 1) ? e2 : e3;
    } else {
        int t = idx - 217088; int s = t >> 14; rel = t & 16383;
        src = (s == 0) ? s1 : (s == 1) ? s2 : s3;
    }
    const float4 v = *(const float4*)(src + (size_t)rel * 4);
    union { unsigned long long q; u16 us[4]; } o;
    o.us[0] = f2b(v.x); o.us[1] = f2b(v.y); o.us[2] = f2b(v.z); o.us[3] = f2b(v.w);
    *(unsigned long long*)(arena + (size_t)idx * 4) = o.q;
}

// ---------------- K1: rmsnorm of x and k -> bf16 ----------------
__global__ __launch_bounds__(256) void rmsnorm_pair(
        const float* __restrict__ x, const float* __restrict__ k,
        const float* __restrict__ w, u16* __restrict__ xn, u16* __restrict__ kn) {
    int row = blockIdx.x * 4 + (threadIdx.x >> 6);
    int lane = threadIdx.x & 63;
    const float* in; u16* out;
    if (row < TOK) { in = x + (size_t)row * 128; out = xn + (size_t)row * 128; }
    else           { in = k + (size_t)(row - TOK) * 128; out = kn + (size_t)(row - TOK) * 128; }
    float2 v = *(const float2*)(in + lane * 2);
    float ss = v.x * v.x + v.y * v.y;
    #pragma unroll
    for (int o = 32; o > 0; o >>= 1) ss += __shfl_xor(ss, o);
    float sc = rsqrtf(ss * (1.f / 128.f) + 1e-6f);
    float2 wv = *(const float2*)(w + lane * 2);
    unsigned pack = ((unsigned)f2b(v.y * sc * wv.y) << 16) | (unsigned)f2b(v.x * sc * wv.x);
    *(unsigned*)(out + lane * 2) = pack;
}

// ---------------- K2: [Tok,128] @ W[128,128]^T + bias -> bf16 (bf16 weights) ----------------
__global__ __launch_bounds__(256) void proj128(
        const u16* __restrict__ in, const u16* __restrict__ W,
        const float* __restrict__ bias, u16* __restrict__ out) {
    int tok0 = blockIdx.x * 128;
    __shared__ u16 sA[128 * 128];
    __shared__ u16 sW[128 * 128];
    int tid = threadIdx.x, lane = tid & 63, ln15 = lane & 15, g16 = lane >> 4, wid = tid >> 6;
    int wm = (wid >> 1) * 64, wn = (wid & 1) * 64;
    stage_bf16<128>(sA, in + (size_t)tok0 * 128, 128, 128, tid, 256);
    stage_bf16<128>(sW, W, 128, 128, tid, 256);
    __syncthreads();
    f32x4 acc[4][4];
    zero_acc(acc);
    #pragma unroll
    for (int ks = 0; ks < 4; ++ks)
        gemm_step64<128, 128>(sA, sW, wm, wn, ks * 64 + g16 * 16, acc, ln15);
    #pragma unroll
    for (int j = 0; j < 4; ++j) {
        int col = wn + j * 16 + ln15;
        float bv = bias[col];
        #pragma unroll
        for (int i = 0; i < 4; ++i)
            #pragma unroll
            for (int r = 0; r < 4; ++r) {
                int row = wm + i * 16 + g16 * 4 + r;
                out[(size_t)(tok0 + row) * 128 + col] = f2b(acc[i][j][r] + bv);
            }
    }
}

// ---------------- K3: attention over T per (b,n), all 4 heads, fused rmsnorm ----------------
__global__ __launch_bounds__(256) void attn_kernel(
        const u16* __restrict__ q, const u16* __restrict__ kk, const u16* __restrict__ vv,
        const float* __restrict__ ntw, u16* __restrict__ txn) {
    int bid = blockIdx.x;
    int b = bid >> 11;
    int n = bid & 2047;
    __shared__ u16 sQ[4][24][32];
    __shared__ u16 sK[4][24][32];
    __shared__ u16 sV[4][24][32];
    __shared__ float sS[4][24][24];
    __shared__ float sO[24][128];
    int tid = threadIdx.x, lane = tid & 63, wid = tid >> 6;
    for (int idx = tid; idx < 3072; idx += 256) {
        int h = idx / 768;
        int rem = idx - h * 768;
        int t = rem >> 5;
        int d = rem & 31;
        size_t off = ((size_t)((b * 24 + t) * 2048 + n)) * 128 + h * 32 + d;
        sQ[h][t][d] = q[off];
        sK[h][t][d] = kk[off];
        sV[h][t][d] = vv[off];
    }
    __syncthreads();
    int h = wid;
    for (int i = lane; i < 576; i += 64) {
        int qi = i / 24, ki = i - qi * 24;
        float s = 0.f;
        #pragma unroll
        for (int c = 0; c < 32; ++c) s += b2f(sQ[h][qi][c]) * b2f(sK[h][ki][c]);
        sS[h][qi][ki] = s * 0.17677669529663687f;   // 32^-0.5
    }
    __syncthreads();
    if (lane < 24) {
        float m = -1e30f;
        #pragma unroll
        for (int c = 0; c < 24; ++c) m = fmaxf(m, sS[h][lane][c]);
        float e[24]; float sum = 0.f;
        #pragma unroll
        for (int c = 0; c < 24; ++c) { e[c] = __expf(sS[h][lane][c] - m); sum += e[c]; }
        float inv = 1.f / sum;
        #pragma unroll
        for (int c = 0; c < 24; ++c) sS[h][lane][c] = e[c] * inv;
    }
    __syncthreads();
    for (int i = lane; i < 768; i += 64) {
        int qi = i >> 5, d = i & 31;
        float acc = 0.f;
        #pragma unroll
        for (int c = 0; c < 24; ++c) acc += sS[h][qi][c] * b2f(sV[h][c][d]);
        sO[qi][h * 32 + d] = acc;
    }
    __syncthreads();
    for (int j = 0; j < 6; ++j) {
        int t = wid * 6 + j;
        float v0 = sO[t][lane], v1 = sO[t][lane + 64];
        float ss = v0 * v0 + v1 * v1;
        #pragma unroll
        for (int o = 32; o > 0; o >>= 1) ss += __shfl_xor(ss, o);
        float sc = rsqrtf(ss * (1.f / 128.f) + 1e-6f);
        size_t off = ((size_t)((b * 24 + t) * 2048 + n)) * 128;
        txn[off + lane]      = f2b(v0 * sc * ntw[lane]);
        txn[off + lane + 64] = f2b(v1 * sc * ntw[lane + 64]);
    }
}

// ---------------- K4: row-normalize adjacency -> bf16 ----------------
__global__ __launch_bounds__(256) void adj_norm(const float* __restrict__ adj, u16* __restrict__ abf) {
    int nrow = blockIdx.x;
    const float* r = adj + (size_t)nrow * 2048;
    int tid = threadIdx.x;
    float s = 0.f;
    for (int c = tid; c < 2048; c += 256) s += r[c];
    __shared__ float red[4];
    #pragma unroll
    for (int o = 32; o > 0; o >>= 1) s += __shfl_xor(s, o);
    if ((tid & 63) == 0) red[tid >> 6] = s;
    __syncthreads();
    float inv = 1.f / (red[0] + red[1] + red[2] + red[3]);
    u16* o = abf + (size_t)nrow * 2048;
    for (int c = tid; c < 2048; c += 256) o[c] = f2b(r[c] * inv);
}

// ---------------- K4t: transpose t_x_n per (b,t): [2048,128] -> [128,2048] ----------------
__global__ __launch_bounds__(256) void transpose_k(const u16* __restrict__ txn, u16* __restrict__ txT) {
    int bt = blockIdx.x >> 5;
    int n0 = (blockIdx.x & 31) * 64;
    int tid = threadIdx.x;
    int nn = tid & 63, dg = tid >> 6;     // 4 d-groups of 8
    for (int rep = 0; rep < 4; ++rep) {
        int d0 = rep * 32 + dg * 8;
        union { u32x4 v; u16 us[8]; } u;
        u.v = *(const u32x4*)(txn + ((size_t)(bt * 2048 + n0 + nn)) * 128 + d0);
        #pragma unroll
        for (int j = 0; j < 8; ++j)
            txT[((size_t)(bt * 128 + d0 + j)) * 2048 + n0 + nn] = u.us[j];
    }
}

// ---------------- K5: GCN mixed = a @ t_x  (per (b,t): [2048,2048]x[2048,128]) ----------------
// m97-structure: async global_load_lds (width=16) with pre-swizzled source.
__global__ __launch_bounds__(256) void gcn_gemm(
        const u16* __restrict__ abf, const u16* __restrict__ txT, u16* __restrict__ mixed) {
    int bt = blockIdx.x >> 4;
    int n0 = (blockIdx.x & 15) * 128;
    __shared__ u16 sA[128 * 64];
    __shared__ u16 sB[128 * 64];
    int tid = threadIdx.x, lane = tid & 63, ln15 = lane & 15, g16 = lane >> 4, wid = tid >> 6;
    int wm = (wid >> 1) * 64, wn = (wid & 1) * 64;
    f32x4 acc[4][4];
    zero_acc(acc);
    const u16* aRow = abf + (size_t)n0 * 2048;
    const u16* bRow = txT + (size_t)bt * 128 * 2048;
    for (int k0 = 0; k0 < 2048; k0 += 64) {
        __syncthreads();                 // previous compute's LDS reads done
        #pragma unroll
        for (int i = 0; i < 4; ++i) stage_async64(sA, aRow + k0, wid * 4 + i, lane);
        #pragma unroll
        for (int i = 0; i < 4; ++i) stage_async64(sB, bRow + k0, wid * 4 + i, lane);
        __syncthreads();                 // compiler drains vmcnt(0) before barrier
        #pragma unroll
        for (int ks = 0; ks < 2; ++ks)
            gemm_step64<64, 64>(sA, sB, wm, wn, ks * 64 + g16 * 16, acc, ln15);
    }
    u16* out = mixed + ((size_t)(bt * 2048 + n0)) * 128;
    #pragma unroll
    for (int i = 0; i < 4; ++i)
        #pragma unroll
        for (int j = 0; j < 4; ++j)
            #pragma unroll
            for (int r = 0; r < 4; ++r) {
                int row = wm + i * 16 + g16 * 4 + r;
                int col = wn + j * 16 + ln15;
                out[(size_t)row * 128 + col] = f2b(acc[i][j][r]);
            }
}

// ---------------- K6: gcn_fc1 + alpha-mix + gcn_mlp + residual + norm2 + router + top2 ----------------
__global__ __launch_bounds__(256) void fused_gcn_router(
        const u16* __restrict__ mixed, const u16* __restrict__ txn,
        const float* __restrict__ x,
        const u16* __restrict__ W1, const u16* __restrict__ W2,
        const float* __restrict__ bias2, const float* __restrict__ n2w,
        const float* __restrict__ gatew,
        float* __restrict__ outx, float* __restrict__ outlog,
        u16* __restrict__ x2n,
        int* __restrict__ lists, float* __restrict__ listw, int* __restrict__ cnts) {
    int tok0 = blockIdx.x * 128;
    __shared__ char LB[65536];
    __shared__ float sGate[1024];
    __shared__ float sN2[128];
    __shared__ float sBias[128];
    __shared__ float sLog[1024];
    __shared__ float sPart[256];
    __shared__ float sScale[128];
    __shared__ int sBCnt[8];
    __shared__ int sGBase[8];
    u16* sM = (u16*)LB;
    u16* sW = (u16*)(LB + 32768);
    float* sXn = (float*)LB;           // overlay, used after GEMM2
    int tid = threadIdx.x, lane = tid & 63, ln15 = lane & 15, g16 = lane >> 4, wid = tid >> 6;
    int wm = (wid >> 1) * 64, wn = (wid & 1) * 64;
    stage_bf16<128>(sM, mixed + (size_t)tok0 * 128, 128, 128, tid, 256);
    stage_bf16<128>(sW, W1, 128, 128, tid, 256);
    for (int i = tid; i < 1024; i += 256) sGate[i] = gatew[i];
    if (tid < 128) { sN2[tid] = n2w[tid]; sBias[tid] = bias2[tid]; }
    if (tid < 8) sBCnt[tid] = 0;
    __syncthreads();
    f32x4 acc[4][4];
    zero_acc(acc);
    #pragma unroll
    for (int ks = 0; ks < 4; ++ks)
        gemm_step64<128, 128>(sM, sW, wm, wn, ks * 64 + g16 * 16, acc, ln15);
    __syncthreads();
    // mixed & W1 dead: stage t_x over sM, W2 over sW
    stage_bf16<128>(sM, txn + (size_t)tok0 * 128, 128, 128, tid, 256);
    stage_bf16<128>(sW, W2, 128, 128, tid, 256);
    __syncthreads();
    // in-place alpha-mix: h = 0.05*t_x + 0.95*gcn_out (per-thread bijective cells)
    #pragma unroll
    for (int i = 0; i < 4; ++i)
        #pragma unroll
        for (int j = 0; j < 4; ++j)
            #pragma unroll
            for (int r = 0; r < 4; ++r) {
                int row = wm + i * 16 + g16 * 4 + r;
                int col = wn + j * 16 + ln15;
                float tv = b2f(lds_us<128>(sM, row, col));
                lds_store_us<128>(sM, row, col, f2b(0.05f * tv + 0.95f * acc[i][j][r]));
            }
    __syncthreads();
    zero_acc(acc);
    #pragma unroll
    for (int ks = 0; ks < 4; ++ks)
        gemm_step64<128, 128>(sM, sW, wm, wn, ks * 64 + g16 * 16, acc, ln15);
    // epilogue in regs: xv = x + ho + bias; write outx; keep xv in acc
    #pragma unroll
    for (int i = 0; i < 4; ++i)
        #pragma unroll
        for (int j = 0; j < 4; ++j)
            #pragma unroll
            for (int r = 0; r < 4; ++r) {
                int row = wm + i * 16 + g16 * 4 + r;
                int col = wn + j * 16 + ln15;
                float xv = x[(size_t)(tok0 + row) * 128 + col] + acc[i][j][r] + sBias[col];
                outx[(size_t)(tok0 + row) * 128 + col] = xv;
                acc[i][j][r] = xv;
            }
    // per-row sum of squares: reduce over 16 lanes (cols of this wave) -> sPart[row][wavehalf]
    #pragma unroll
    for (int i = 0; i < 4; ++i)
        #pragma unroll
        for (int r = 0; r < 4; ++r) {
            float s = 0.f;
            #pragma unroll
            for (int j = 0; j < 4; ++j) s += acc[i][j][r] * acc[i][j][r];
            s += __shfl_xor(s, 1); s += __shfl_xor(s, 2);
            s += __shfl_xor(s, 4); s += __shfl_xor(s, 8);
            if (ln15 == 0) sPart[(wm + i * 16 + g16 * 4 + r) * 2 + (wid & 1)] = s;
        }
    __syncthreads();   // also guarantees GEMM2's LDS reads are done before sXn overlay
    if (tid < 128)
        sScale[tid] = rsqrtf((sPart[tid * 2] + sPart[tid * 2 + 1]) * (1.f / 128.f) + 1e-6f);
    __syncthreads();
    // write f32 normalized tile into the 64KB overlay
    #pragma unroll
    for (int i = 0; i < 4; ++i)
        #pragma unroll
        for (int j = 0; j < 4; ++j)
            #pragma unroll
            for (int r = 0; r < 4; ++r) {
                int row = wm + i * 16 + g16 * 4 + r;
                int col = wn + j * 16 + ln15;
                sXn[row * 128 + col] = acc[i][j][r] * sScale[row] * sN2[col];
            }
    __syncthreads();
    {   // router logits (2 threads per row x 4 experts each); rotate c by r to dodge banks
        int r = tid >> 1, e0 = (tid & 1) * 4;
        float a0 = 0, a1 = 0, a2 = 0, a3 = 0;
        for (int cc = 0; cc < 128; ++cc) {
            int c = (cc + r) & 127;
            float v = sXn[r * 128 + c];
            a0 += v * sGate[(e0 + 0) * 128 + c];
            a1 += v * sGate[(e0 + 1) * 128 + c];
            a2 += v * sGate[(e0 + 2) * 128 + c];
            a3 += v * sGate[(e0 + 3) * 128 + c];
        }
        int rb = r * 8 + e0;
        sLog[rb + 0] = a0; sLog[rb + 1] = a1; sLog[rb + 2] = a2; sLog[rb + 3] = a3;
        size_t ob = (size_t)(tok0 + r) * 8 + e0;
        outlog[ob + 0] = a0; outlog[ob + 1] = a1; outlog[ob + 2] = a2; outlog[ob + 3] = a3;
    }
    // x2n store (bf16, vectorized) straight from the f32 overlay
    for (int cc = tid; cc < 2048; cc += 256) {
        int r = cc >> 4, c0 = (cc & 15) * 8;
        union { u32x4 v; u16 us[8]; } u;
        #pragma unroll
        for (int jj = 0; jj < 8; ++jj) u.us[jj] = f2b(sXn[r * 128 + c0 + jj]);
        *(u32x4*)(x2n + (size_t)(tok0 + r) * 128 + c0) = u.v;
    }
    __syncthreads();
    // top-2 with BLOCK-AGGREGATED list build (8 global atomics per block)
    // list payload = tok*2 + slot  (slot 0 = top-1 entry, 1 = top-2 entry)
    int e1 = 0, e2 = 0, le1 = 0, le2 = 0;
    float w1v = 0.f, w2v = 0.f;
    if (tid < 128) {
        int r = tid;
        float l[8];
        #pragma unroll
        for (int e = 0; e < 8; ++e) l[e] = sLog[r * 8 + e];
        float m = l[0];
        #pragma unroll
        for (int e = 1; e < 8; ++e) m = fmaxf(m, l[e]);
        float ex[8]; float s = 0.f;
        #pragma unroll
        for (int e = 0; e < 8; ++e) { ex[e] = __expf(l[e] - m); s += ex[e]; }
        float inv = 1.f / s;
        float b1v = ex[0]; e1 = 0;
        #pragma unroll
        for (int e = 1; e < 8; ++e) if (ex[e] > b1v) { b1v = ex[e]; e1 = e; }
        e2 = (e1 == 0) ? 1 : 0; float b2v = ex[e2];
        #pragma unroll
        for (int e = 0; e < 8; ++e) if (e != e1 && ex[e] > b2v) { b2v = ex[e]; e2 = e; }
        w1v = b1v * inv; w2v = b2v * inv;
        le1 = atomicAdd(&sBCnt[e1], 1);
        le2 = atomicAdd(&sBCnt[e2], 1);
    }
    __syncthreads();
    if (tid < 8) sGBase[tid] = atomicAdd(&cnts[tid], sBCnt[tid]);
    __syncthreads();
    if (tid < 128) {
        int tok = tok0 + tid;
        int p1 = sGBase[e1] + le1;
        lists[(size_t)e1 * TOK + p1] = tok * 2 + 0; listw[(size_t)e1 * TOK + p1] = w1v;
        int p2 = sGBase[e2] + le2;
        lists[(size_t)e2 * TOK + p2] = tok * 2 + 1; listw[(size_t)e2 * TOK + p2] = w2v;
    }
}

// ---------------- K7: sparse expert swiglu: direct-reg A frags, single 26KB buf, 3 blk/CU ----------------
__global__ __launch_bounds__(256, 3) void moe_expert(
        const u16* __restrict__ x2n, const int* __restrict__ lists,
        const float* __restrict__ listw, const int* __restrict__ cnts,
        const u16* __restrict__ bw1, const u16* __restrict__ bw2,
        const u16* __restrict__ bw3, u16* __restrict__ slotOut) {
    int e = blockIdx.y;
    int base = blockIdx.x * 128;
    int cnt = cnts[e];
    if (base >= cnt) return;
    int valid = min(128, cnt - base);
    const int* lst = lists + (size_t)e * TOK + base;
    const float* lw = listw + (size_t)e * TOK + base;
    __shared__ u16 sBuf[13312];        // 26624B weight chunk
    __shared__ u16 sH[5120];           // 128 rows x 80B
    __shared__ float sCoef[128];
    __shared__ int sTok[128];
    int tid = threadIdx.x, lane = tid & 63, ln15 = lane & 15, g16 = lane >> 4, wid = tid >> 6;
    if (tid < 128) {
        int t = (tid < valid) ? lst[tid] : -1;
        sTok[tid] = t;
        sCoef[tid] = (tid < valid) ? lw[tid] : 0.f;
    }
    const u16* w1base = bw1 + (size_t)e * (256 * 128);
    const u16* w3base = bw3 + (size_t)e * (256 * 128);
    const u16* w2base = bw2 + (size_t)e * (128 * 256);
    u32x4 pf0[6];
    prefetch_regs(pf0, w1base, w3base, w2base, 256, tid);
    __syncthreads();                    // sTok/sCoef visible
    // A-fragments gathered directly global->reg (each block byte read once)
    bf16x8 av[2][4];
    {
        bf16x8 zz = {0, 0, 0, 0, 0, 0, 0, 0};
        int t0 = sTok[wid * 32 + ln15];
        int t1 = sTok[wid * 32 + 16 + ln15];
        const u16* r0 = x2n + (size_t)(t0 >> 1) * 128;
        const u16* r1 = x2n + (size_t)(t1 >> 1) * 128;
        #pragma unroll
        for (int ks = 0; ks < 4; ++ks) {
            av[0][ks] = (t0 >= 0) ? *(const bf16x8*)(r0 + ks * 32 + g16 * 8) : zz;
            av[1][ks] = (t1 >= 0) ? *(const bf16x8*)(r1 + ks * 32 + g16 * 8) : zz;
        }
    }
    write_chunk(sBuf, pf0, tid);
    __syncthreads();
    f32x4 aout[2][8];
    f32x4 z = {0.f, 0.f, 0.f, 0.f};
    #pragma unroll
    for (int mf = 0; mf < 2; ++mf)
        #pragma unroll
        for (int nf = 0; nf < 8; ++nf) aout[mf][nf] = z;
    for (int ic = 0; ic < 8; ++ic) {
        u32x4 pf[6];
        bool hasNext = (ic + 1 < 8);
        if (hasNext)
            prefetch_regs(pf, w1base + (ic + 1) * 4096, w3base + (ic + 1) * 4096,
                          w2base + (ic + 1) * 32, 256, tid);
        swiglu_chunk(sBuf, sH, av, aout, wid, g16, ln15);
        if (hasNext) {
            __syncthreads();           // all reads of sBuf done
            write_chunk(sBuf, pf, tid);
            __syncthreads();           // next chunk visible
        }
    }
    #pragma unroll
    for (int mf = 0; mf < 2; ++mf)
        #pragma unroll
        for (int nf = 0; nf < 8; ++nf)
            #pragma unroll
            for (int r = 0; r < 4; ++r) {
                int row = wid * 32 + mf * 16 + g16 * 4 + r;
                if (row < valid) {
                    int col = nf * 16 + ln15;
                    slotOut[(size_t)sTok[row] * 128 + col] = f2b(sCoef[row] * aout[mf][nf][r]);
                }
            }
}

// ---------------- K8: shared expert swiglu: direct-reg A frags, single buf, + gate + combine ----------------
__global__ __launch_bounds__(256, 3) void moe_shared(
        const u16* __restrict__ x2n, const u16* __restrict__ bw1,
        const u16* __restrict__ bw2, const u16* __restrict__ bw3,
        const float* __restrict__ sgw, const u16* __restrict__ slotOut,
        float* __restrict__ outx) {
    int tok0 = blockIdx.x * 128;
    __shared__ u16 sBuf[13312];
    __shared__ u16 sH[5120];
    __shared__ float sGv[128];
    int tid = threadIdx.x, lane = tid & 63, ln15 = lane & 15, g16 = lane >> 4, wid = tid >> 6;
    u32x4 pf0[6];
    prefetch_regs(pf0, bw1, bw3, bw2, 512, tid);
    // A-fragments direct global->reg (consecutive tokens: fully coalesced)
    bf16x8 av[2][4];
    {
        const u16* r0 = x2n + (size_t)(tok0 + wid * 32 + ln15) * 128;
        const u16* r1 = x2n + (size_t)(tok0 + wid * 32 + 16 + ln15) * 128;
        #pragma unroll
        for (int ks = 0; ks < 4; ++ks) {
            av[0][ks] = *(const bf16x8*)(r0 + ks * 32 + g16 * 8);
            av[1][ks] = *(const bf16x8*)(r1 + ks * 32 + g16 * 8);
        }
    }
    // sigmoid gate dot straight from global (sgw broadcast, x2n row per thread)
    if (tid < 128) {
        const u16* xr = x2n + (size_t)(tok0 + tid) * 128;
        float d = 0.f;
        #pragma unroll
        for (int c8 = 0; c8 < 16; ++c8) {
            bf16x8 v = *(const bf16x8*)(xr + c8 * 8);
            #pragma unroll
            for (int j = 0; j < 8; ++j) d += b2f((u16)v[j]) * sgw[c8 * 8 + j];
        }
        sGv[tid] = 1.f / (1.f + __expf(-d));
    }
    write_chunk(sBuf, pf0, tid);
    __syncthreads();
    f32x4 aout[2][8];
    f32x4 z = {0.f, 0.f, 0.f, 0.f};
    #pragma unroll
    for (int mf = 0; mf < 2; ++mf)
        #pragma unroll
        for (int nf = 0; nf < 8; ++nf) aout[mf][nf] = z;
    for (int ic = 0; ic < 16; ++ic) {
        u32x4 pf[6];
        bool hasNext = (ic + 1 < 16);
        if (hasNext)
            prefetch_regs(pf, bw1 + (ic + 1) * 4096, bw3 + (ic + 1) * 4096,
                          bw2 + (ic + 1) * 32, 512, tid);
        swiglu_chunk(sBuf, sH, av, aout, wid, g16, ln15);
        if (hasNext) {
            __syncthreads();
            write_chunk(sBuf, pf, tid);
            __syncthreads();
        }
    }
    #pragma unroll
    for (int mf = 0; mf < 2; ++mf)
        #pragma unroll
        for (int nf = 0; nf < 8; ++nf)
            #pragma unroll
            for (int r = 0; r < 4; ++r) {
                int row = wid * 32 + mf * 16 + g16 * 4 + r;
                int col = nf * 16 + ln15;
                size_t t = (size_t)(tok0 + row);
                float fc = b2f(slotOut[(t * 2 + 0) * 128 + col])
                         + b2f(slotOut[(t * 2 + 1) * 128 + col]);
                size_t idx = t * 128 + col;
                outx[idx] = outx[idx] + fc + sGv[row] * aout[mf][nf][r];
            }
}

// ---------------- host launcher ----------------
// workspace layout (bytes)
#define SZTD  ((size_t)TOK * 128 * 2)          // 50331648, one bf16 [Tok,128] buffer
#define OFF_XN   ((size_t)0)                   // x_n -> t_x_n
#define OFF_KN   (SZTD)                        // k_n -> mixed
#define OFF_Q    (SZTD * 2)                    // q -> t_xT -> x2n
#define OFF_KP   (SZTD * 3)                    // kp ; later slotOut bf16 [2*TOK][128] spans KP..KP+SZTD*2
#define OFF_VP   (SZTD * 4)                    // vp
#define OFF_ABF  (SZTD * 5)                    // a bf16 [2048,2048] = 8388608
#define OFF_LW   (OFF_ABF + 8388608)           // listw f32 [8*TOK]
#define OFF_LIST (OFF_LW + (size_t)8 * TOK * 4)
#define OFF_CNT  (OFF_LIST + (size_t)8 * TOK * 4)
#define OFF_ARENA (OFF_CNT + 128)              // bf16 weights arena, 1064960 elems

extern "C" void kernel_launch(void* const* d_in, const int* in_sizes, int n_in,
                              void* d_out, int out_size, void* d_ws, size_t ws_size,
                              hipStream_t stream) {
    (void)in_sizes; (void)n_in; (void)out_size; (void)ws_size;
    const float* x    = (const float*)d_in[0];
    const float* k    = (const float*)d_in[1];
    // d_in[2] (v) is unused by the reference
    const float* adj  = (const float*)d_in[3];
    const float* Wq   = (const float*)d_in[4];
    const float* bq   = (const float*)d_in[5];
    const float* Wk   = (const float*)d_in[6];
    const float* bk   = (const float*)d_in[7];
    const float* Wv   = (const float*)d_in[8];
    const float* bv   = (const float*)d_in[9];
    const float* ntw  = (const float*)d_in[10];
    const float* gfc1 = (const float*)d_in[11];
    const float* gmlp = (const float*)d_in[12];
    const float* gmlpb= (const float*)d_in[13];
    const float* n1w  = (const float*)d_in[14];
    const float* n2w  = (const float*)d_in[15];
    const float* gatew= (const float*)d_in[16];
    const float* ew1  = (const float*)d_in[17];
    const float* ew2  = (const float*)d_in[18];
    const float* ew3  = (const float*)d_in[19];
    const float* sw1  = (const float*)d_in[20];
    const float* sw2  = (const float*)d_in[21];
    const float* sw3  = (const float*)d_in[22];
    const float* sgw  = (const float*)d_in[23];

    char* ws = (char*)d_ws;
    u16*  xn   = (u16*)(ws + OFF_XN);
    u16*  kn   = (u16*)(ws + OFF_KN);
    u16*  qb   = (u16*)(ws + OFF_Q);
    u16*  kpb  = (u16*)(ws + OFF_KP);
    u16*  vpb  = (u16*)(ws + OFF_VP);
    u16*  slotOut = (u16*)(ws + OFF_KP);      // overlaps kp+vp (dead after attention)
    u16*  abf  = (u16*)(ws + OFF_ABF);
    float* lw  = (float*)(ws + OFF_LW);
    int*  lst  = (int*)(ws + OFF_LIST);
    int*  cnts = (int*)(ws + OFF_CNT);
    u16*  arena = (u16*)(ws + OFF_ARENA);
    u16*  bWq = arena;
    u16*  bWk = arena + 16384;
    u16*  bWv = arena + 32768;
    u16*  bG1 = arena + 49152;
    u16*  bG2 = arena + 65536;
    u16*  bE1 = arena + 81920;
    u16*  bE2 = arena + 344064;
    u16*  bE3 = arena + 606208;
    u16*  bS1 = arena + 868352;
    u16*  bS2 = arena + 933888;
    u16*  bS3 = arena + 999424;
    float* outx   = (float*)d_out;
    float* outlog = outx + (size_t)TOK * 128;

    preconvert<<<1040, 256, 0, stream>>>(Wq, Wk, Wv, gfc1, gmlp, ew1, ew2, ew3,
                                         sw1, sw2, sw3, arena, cnts);
    rmsnorm_pair<<<98304, 256, 0, stream>>>(x, k, n1w, xn, kn);
    proj128<<<1536, 256, 0, stream>>>(xn, bWq, bq, qb);
    proj128<<<1536, 256, 0, stream>>>(kn, bWk, bk, kpb);
    proj128<<<1536, 256, 0, stream>>>(kn, bWv, bv, vpb);
    attn_kernel<<<8192, 256, 0, stream>>>(qb, kpb, vpb, ntw, xn /* t_x_n */);
    adj_norm<<<2048, 256, 0, stream>>>(adj, abf);
    transpose_k<<<3072, 256, 0, stream>>>(xn, qb /* t_xT */);
    gcn_gemm<<<1536, 256, 0, stream>>>(abf, qb, kn /* mixed */);
    fused_gcn_router<<<1536, 256, 0, stream>>>(kn, xn, x, bG1, bG2, gmlpb, n2w, gatew,
                                               outx, outlog, qb /* x2n */, lst, lw, cnts);
    moe_expert<<<dim3(1536, 8), 256, 0, stream>>>(qb, lst, lw, cnts, bE1, bE2, bE3, slotOut);
    moe_shared<<<1536, 256, 0, stream>>>(qb, bS1, bS2, bS3, sgw, slotOut, outx);
}

// Round 8
// 778.158 us; speedup vs baseline: 1.4318x; 1.4318x over previous
//
#include <hip/hip_runtime.h>

// ---------------- problem constants ----------------
#define BB 4
#define TT 24
#define NN 2048
#define DD 128
#define HH 4
#define HD 32
#define TOK 196608          // BB*TT*NN
#define EE 8
#define MINTER 256
#define INTER 512

typedef unsigned short u16;
typedef __attribute__((ext_vector_type(8))) short  bf16x8;
typedef __attribute__((ext_vector_type(4))) float  f32x4;
typedef __attribute__((ext_vector_type(4))) unsigned int u32x4;

#define MFMA(a,b,c) __builtin_amdgcn_mfma_f32_16x16x32_bf16((a),(b),(c),0,0,0)
#define AS(n) __attribute__((address_space(n)))

// ---------------- small helpers ----------------
static __device__ __forceinline__ u16 f2b(float f) {
    union { float f; unsigned u; } v; v.f = f;
    unsigned r = v.u + 0x7FFFu + ((v.u >> 16) & 1u);
    return (u16)(r >> 16);
}
static __device__ __forceinline__ float b2f(u16 b) {
    union { unsigned u; float f; } v; v.u = ((unsigned)b) << 16;
    return v.f;
}
static __device__ __forceinline__ float silu_mul(float u, float v) {
    return u * __builtin_amdgcn_rcpf(1.f + __expf(-u)) * v;
}

// LDS tile helpers.  Tiles are [rows][C] bf16, row stride C*2 bytes, with a
// 16B-chunk XOR swizzle: chunk cc of row r lives at byte r*C*2 + ((cc*16) ^ ((r&mask)<<4)).
template<int C>
static __device__ __forceinline__ bf16x8 frag_ld(const u16* s, int row, int kbyte) {
    constexpr int mask = ((C/8) < 8 ? (C/8) : 8) - 1;
    int byte = row * (C * 2) + (kbyte ^ ((row & mask) << 4));
    return *(const bf16x8*)((const char*)s + byte);
}
template<int C>
static __device__ __forceinline__ u16 lds_us(const u16* s, int r, int c) {
    constexpr int mask = ((C/8) < 8 ? (C/8) : 8) - 1;
    int byte = r * (C * 2) + ((((c >> 3) << 4) ^ ((r & mask) << 4))) + ((c & 7) << 1);
    return *(const u16*)((const char*)s + byte);
}
template<int C>
static __device__ __forceinline__ void lds_store_us(u16* s, int r, int c, u16 v) {
    constexpr int mask = ((C/8) < 8 ? (C/8) : 8) - 1;
    int byte = r * (C * 2) + ((((c >> 3) << 4) ^ ((r & mask) << 4))) + ((c & 7) << 1);
    *(u16*)((char*)s + byte) = v;
}
// 80B-padded row stride (period-8 bank pattern, conflict-free for 16B reads)
static __device__ __forceinline__ bf16x8 frag_ld_p80(const u16* s, int row, int kbyte) {
    return *(const bf16x8*)((const char*)s + row * 80 + kbyte);
}
static __device__ __forceinline__ void sh_store_p80(u16* s, int r, int c, u16 v) {
    *(u16*)((char*)s + r * 80 + c * 2) = v;
}
// stage bf16 global -> swizzled LDS tile (reg path)
template<int C>
static __device__ __forceinline__ void stage_bf16(u16* s, const u16* g, int gstride,
                                                  int rows, int tid, int nthr) {
    constexpr int cpr = C / 8;
    constexpr int mask = (cpr < 8 ? cpr : 8) - 1;
    for (int i = tid; i < rows * cpr; i += nthr) {
        int r = i / cpr, cc = i - r * cpr;
        u32x4 v = *(const u32x4*)(g + (size_t)r * gstride + cc * 8);
        *(u32x4*)((char*)s + r * (C * 2) + ((cc * 16) ^ ((r & mask) << 4))) = v;
    }
}
// async stage for a [128][64] bf16 tile from row-major global (stride 2048):
// LDS linear dest (wave base + lane*16), PRE-SWIZZLED global source chunk.
static __device__ __forceinline__ void stage_async64(u16* s, const u16* g, int wi, int lane) {
    int slot = wi * 64 + lane;            // 16B-chunk index in [0,1024)
    int r = slot >> 3, c = slot & 7;
    const u16* src = g + r * 2048 + ((c ^ (r & 7)) << 3);
    __builtin_amdgcn_global_load_lds((const AS(1) void*)src,
                                     (AS(3) void*)(s + wi * 512), 16, 0, 0);
}
static __device__ __forceinline__ void zero_acc(f32x4 acc[4][4]) {
    f32x4 z = {0.f, 0.f, 0.f, 0.f};
    #pragma unroll
    for (int i = 0; i < 4; ++i)
        #pragma unroll
        for (int j = 0; j < 4; ++j) acc[i][j] = z;
}
// one K-step (32) of a 64x64 wave tile: 4 A frags x 4 B frags -> 16 MFMA
template<int CA, int CB>
static __device__ __forceinline__ void gemm_step64(const u16* sA, const u16* sB,
        int arow0, int brow0, int kbyte, f32x4 acc[4][4], int ln15) {
    bf16x8 a[4], b[4];
    #pragma unroll
    for (int i = 0; i < 4; ++i) a[i] = frag_ld<CA>(sA, arow0 + i * 16 + ln15, kbyte);
    #pragma unroll
    for (int j = 0; j < 4; ++j) b[j] = frag_ld<CB>(sB, brow0 + j * 16 + ln15, kbyte);
    #pragma unroll
    for (int i = 0; i < 4; ++i)
        #pragma unroll
        for (int j = 0; j < 4; ++j)
            acc[i][j] = MFMA(a[i], b[j], acc[i][j]);
}

// ---- MoE weight-chunk prefetch (T14 issue-early / write-late) ----
// LDS chunk layout (bytes): W1c [32][128] swz @0 (8KB), W3c swz @8192 (8KB),
// W2c [128] rows @16384 with 80B padded stride (10240B). Total 26624B.
static __device__ __forceinline__ void prefetch_regs(u32x4 pf[6],
        const u16* __restrict__ w1b, const u16* __restrict__ w3b,
        const u16* __restrict__ w2b, int w2s, int tid) {
    #pragma unroll
    for (int p = 0; p < 6; ++p) {
        int i = p * 256 + tid;
        const u16* src;
        if (i < 512)       { int r = i >> 4, cc = i & 15; src = w1b + r * 128 + cc * 8; }
        else if (i < 1024) { int j = i - 512; int r = j >> 4, cc = j & 15; src = w3b + r * 128 + cc * 8; }
        else               { int j = i - 1024; int r = j >> 2, cc = j & 3; src = w2b + (size_t)r * w2s + cc * 8; }
        pf[p] = *(const u32x4*)src;
    }
}
static __device__ __forceinline__ void write_chunk(u16* buf, const u32x4 pf[6], int tid) {
    #pragma unroll
    for (int p = 0; p < 6; ++p) {
        int i = p * 256 + tid;
        char* dst;
        if (i < 512)       { int r = i >> 4, cc = i & 15; dst = (char*)buf + r * 256 + ((cc * 16) ^ ((r & 7) << 4)); }
        else if (i < 1024) { int j = i - 512; int r = j >> 4, cc = j & 15; dst = (char*)buf + 8192 + r * 256 + ((cc * 16) ^ ((r & 7) << 4)); }
        else               { int j = i - 1024; int r = j >> 2, cc = j & 3; dst = (char*)buf + 16384 + r * 80 + cc * 16; }
        *(u32x4*)dst = pf[p];
    }
}
// one swiglu inter-chunk (32 wide): p1 (W1,W3) -> silu -> sH -> p2 accumulate into aout
static __device__ __forceinline__ void swiglu_chunk(const u16* buf, u16* sH,
        const bf16x8 av[2][4], f32x4 aout[2][8],
        int wid, int g16, int ln15) {
    const u16* W1c = buf;               // 32 rows, swz128
    const u16* W3c = buf + 4096;        // 32 rows, swz128
    const u16* W2c = buf + 8192;        // 128 rows, 80B padded
    f32x4 z = {0.f, 0.f, 0.f, 0.f};
    f32x4 a1[2][2], a3[2][2];
    #pragma unroll
    for (int mf = 0; mf < 2; ++mf)
        #pragma unroll
        for (int nf = 0; nf < 2; ++nf) { a1[mf][nf] = z; a3[mf][nf] = z; }
    #pragma unroll
    for (int ks = 0; ks < 4; ++ks) {
        int kb = ks * 64 + g16 * 16;
        #pragma unroll
        for (int nf = 0; nf < 2; ++nf) {
            bf16x8 b1 = frag_ld<128>(W1c, nf * 16 + ln15, kb);
            bf16x8 b3 = frag_ld<128>(W3c, nf * 16 + ln15, kb);
            a1[0][nf] = MFMA(av[0][ks], b1, a1[0][nf]);
            a1[1][nf] = MFMA(av[1][ks], b1, a1[1][nf]);
            a3[0][nf] = MFMA(av[0][ks], b3, a3[0][nf]);
            a3[1][nf] = MFMA(av[1][ks], b3, a3[1][nf]);
        }
    }
    #pragma unroll
    for (int mf = 0; mf < 2; ++mf)
        #pragma unroll
        for (int nf = 0; nf < 2; ++nf)
            #pragma unroll
            for (int r = 0; r < 4; ++r) {
                int row = wid * 32 + mf * 16 + g16 * 4 + r;
                int col = nf * 16 + ln15;
                sh_store_p80(sH, row, col, f2b(silu_mul(a1[mf][nf][r], a3[mf][nf][r])));
            }
    // sH rows are wave-private: wave w writes & reads only rows w*32..w*32+31
    asm volatile("s_waitcnt lgkmcnt(0)" ::: "memory");
    __builtin_amdgcn_sched_barrier(0);
    {
        int kb = g16 * 16;
        bf16x8 ah0 = frag_ld_p80(sH, wid * 32 + ln15, kb);
        bf16x8 ah1 = frag_ld_p80(sH, wid * 32 + 16 + ln15, kb);
        #pragma unroll
        for (int nf = 0; nf < 8; ++nf) {
            bf16x8 bw = frag_ld_p80(W2c, nf * 16 + ln15, kb);
            aout[0][nf] = MFMA(ah0, bw, aout[0][nf]);
            aout[1][nf] = MFMA(ah1, bw, aout[1][nf]);
        }
    }
}

// ---------------- K0: preconvert all weight matrices f32 -> bf16 arena; zero cnts ----------------
__global__ __launch_bounds__(256) void preconvert(
        const float* __restrict__ Wq, const float* __restrict__ Wk,
        const float* __restrict__ Wv, const float* __restrict__ g1,
        const float* __restrict__ g2,
        const float* __restrict__ e1, const float* __restrict__ e2,
        const float* __restrict__ e3,
        const float* __restrict__ s1, const float* __restrict__ s2,
        const float* __restrict__ s3,
        u16* __restrict__ arena, int* __restrict__ cnts) {
    int idx = blockIdx.x * 256 + threadIdx.x;
    if (blockIdx.x == 0 && threadIdx.x < 8) cnts[threadIdx.x] = 0;
    if (idx >= 266240) return;
    const float* src; int rel;
    if (idx < 20480) {
        int s = idx >> 12; rel = idx & 4095;
        src = (s == 0) ? Wq : (s == 1) ? Wk : (s == 2) ? Wv : (s == 3) ? g1 : g2;
    } else if (idx < 217088) {
        int t = idx - 20480; int s = t >> 16; rel = t & 65535;
        src = (s == 0) ? e1 : (s == 1) ? e2 : e3;
    } else {
        int t = idx - 217088; int s = t >> 14; rel = t & 16383;
        src = (s == 0) ? s1 : (s == 1) ? s2 : s3;
    }
    const float4 v = *(const float4*)(src + (size_t)rel * 4);
    union { unsigned long long q; u16 us[4]; } o;
    o.us[0] = f2b(v.x); o.us[1] = f2b(v.y); o.us[2] = f2b(v.z); o.us[3] = f2b(v.w);
    *(unsigned long long*)(arena + (size_t)idx * 4) = o.q;
}

// ---------------- K1: rmsnorm of x and k -> bf16 ----------------
__global__ __launch_bounds__(256) void rmsnorm_pair(
        const float* __restrict__ x, const float* __restrict__ k,
        const float* __restrict__ w, u16* __restrict__ xn, u16* __restrict__ kn) {
    int row = blockIdx.x * 4 + (threadIdx.x >> 6);
    int lane = threadIdx.x & 63;
    const float* in; u16* out;
    if (row < TOK) { in = x + (size_t)row * 128; out = xn + (size_t)row * 128; }
    else           { in = k + (size_t)(row - TOK) * 128; out = kn + (size_t)(row - TOK) * 128; }
    float2 v = *(const float2*)(in + lane * 2);
    float ss = v.x * v.x + v.y * v.y;
    #pragma unroll
    for (int o = 32; o > 0; o >>= 1) ss += __shfl_xor(ss, o);
    float sc = rsqrtf(ss * (1.f / 128.f) + 1e-6f);
    float2 wv = *(const float2*)(w + lane * 2);
    unsigned pack = ((unsigned)f2b(v.y * sc * wv.y) << 16) | (unsigned)f2b(v.x * sc * wv.x);
    *(unsigned*)(out + lane * 2) = pack;
}

// ---------------- K2: [Tok,128] @ W[128,128]^T + bias -> bf16 (bf16 weights) ----------------
__global__ __launch_bounds__(256) void proj128(
        const u16* __restrict__ in, const u16* __restrict__ W,
        const float* __restrict__ bias, u16* __restrict__ out) {
    int tok0 = blockIdx.x * 128;
    __shared__ u16 sA[128 * 128];
    __shared__ u16 sW[128 * 128];
    int tid = threadIdx.x, lane = tid & 63, ln15 = lane & 15, g16 = lane >> 4, wid = tid >> 6;
    int wm = (wid >> 1) * 64, wn = (wid & 1) * 64;
    stage_bf16<128>(sA, in + (size_t)tok0 * 128, 128, 128, tid, 256);
    stage_bf16<128>(sW, W, 128, 128, tid, 256);
    __syncthreads();
    f32x4 acc[4][4];
    zero_acc(acc);
    #pragma unroll
    for (int ks = 0; ks < 4; ++ks)
        gemm_step64<128, 128>(sA, sW, wm, wn, ks * 64 + g16 * 16, acc, ln15);
    #pragma unroll
    for (int j = 0; j < 4; ++j) {
        int col = wn + j * 16 + ln15;
        float bv = bias[col];
        #pragma unroll
        for (int i = 0; i < 4; ++i)
            #pragma unroll
            for (int r = 0; r < 4; ++r) {
                int row = wm + i * 16 + g16 * 4 + r;
                out[(size_t)(tok0 + row) * 128 + col] = f2b(acc[i][j][r] + bv);
            }
    }
}

// ---------------- K3: attention over T per (b,n), all 4 heads, fused rmsnorm ----------------
__global__ __launch_bounds__(256) void attn_kernel(
        const u16* __restrict__ q, const u16* __restrict__ kk, const u16* __restrict__ vv,
        const float* __restrict__ ntw, u16* __restrict__ txn) {
    int bid = blockIdx.x;
    int b = bid >> 11;
    int n = bid & 2047;
    __shared__ u16 sQ[4][24][32];
    __shared__ u16 sK[4][24][32];
    __shared__ u16 sV[4][24][32];
    __shared__ float sS[4][24][24];
    __shared__ float sO[24][128];
    int tid = threadIdx.x, lane = tid & 63, wid = tid >> 6;
    for (int idx = tid; idx < 3072; idx += 256) {
        int h = idx / 768;
        int rem = idx - h * 768;
        int t = rem >> 5;
        int d = rem & 31;
        size_t off = ((size_t)((b * 24 + t) * 2048 + n)) * 128 + h * 32 + d;
        sQ[h][t][d] = q[off];
        sK[h][t][d] = kk[off];
        sV[h][t][d] = vv[off];
    }
    __syncthreads();
    int h = wid;
    for (int i = lane; i < 576; i += 64) {
        int qi = i / 24, ki = i - qi * 24;
        float s = 0.f;
        #pragma unroll
        for (int c = 0; c < 32; ++c) s += b2f(sQ[h][qi][c]) * b2f(sK[h][ki][c]);
        sS[h][qi][ki] = s * 0.17677669529663687f;   // 32^-0.5
    }
    __syncthreads();
    if (lane < 24) {
        float m = -1e30f;
        #pragma unroll
        for (int c = 0; c < 24; ++c) m = fmaxf(m, sS[h][lane][c]);
        float e[24]; float sum = 0.f;
        #pragma unroll
        for (int c = 0; c < 24; ++c) { e[c] = __expf(sS[h][lane][c] - m); sum += e[c]; }
        float inv = 1.f / sum;
        #pragma unroll
        for (int c = 0; c < 24; ++c) sS[h][lane][c] = e[c] * inv;
    }
    __syncthreads();
    for (int i = lane; i < 768; i += 64) {
        int qi = i >> 5, d = i & 31;
        float acc = 0.f;
        #pragma unroll
        for (int c = 0; c < 24; ++c) acc += sS[h][qi][c] * b2f(sV[h][c][d]);
        sO[qi][h * 32 + d] = acc;
    }
    __syncthreads();
    for (int j = 0; j < 6; ++j) {
        int t = wid * 6 + j;
        float v0 = sO[t][lane], v1 = sO[t][lane + 64];
        float ss = v0 * v0 + v1 * v1;
        #pragma unroll
        for (int o = 32; o > 0; o >>= 1) ss += __shfl_xor(ss, o);
        float sc = rsqrtf(ss * (1.f / 128.f) + 1e-6f);
        size_t off = ((size_t)((b * 24 + t) * 2048 + n)) * 128;
        txn[off + lane]      = f2b(v0 * sc * ntw[lane]);
        txn[off + lane + 64] = f2b(v1 * sc * ntw[lane + 64]);
    }
}

// ---------------- K4: row-normalize adjacency -> bf16 ----------------
__global__ __launch_bounds__(256) void adj_norm(const float* __restrict__ adj, u16* __restrict__ abf) {
    int nrow = blockIdx.x;
    const float* r = adj + (size_t)nrow * 2048;
    int tid = threadIdx.x;
    float s = 0.f;
    for (int c = tid; c < 2048; c += 256) s += r[c];
    __shared__ float red[4];
    #pragma unroll
    for (int o = 32; o > 0; o >>= 1) s += __shfl_xor(s, o);
    if ((tid & 63) == 0) red[tid >> 6] = s;
    __syncthreads();
    float inv = 1.f / (red[0] + red[1] + red[2] + red[3]);
    u16* o = abf + (size_t)nrow * 2048;
    for (int c = tid; c < 2048; c += 256) o[c] = f2b(r[c] * inv);
}

// ---------------- K4t: transpose t_x_n per (b,t): [2048,128] -> [128,2048] ----------------
__global__ __launch_bounds__(256) void transpose_k(const u16* __restrict__ txn, u16* __restrict__ txT) {
    int bt = blockIdx.x >> 5;
    int n0 = (blockIdx.x & 31) * 64;
    int tid = threadIdx.x;
    int nn = tid & 63, dg = tid >> 6;     // 4 d-groups of 8
    for (int rep = 0; rep < 4; ++rep) {
        int d0 = rep * 32 + dg * 8;
        union { u32x4 v; u16 us[8]; } u;
        u.v = *(const u32x4*)(txn + ((size_t)(bt * 2048 + n0 + nn)) * 128 + d0);
        #pragma unroll
        for (int j = 0; j < 8; ++j)
            txT[((size_t)(bt * 128 + d0 + j)) * 2048 + n0 + nn] = u.us[j];
    }
}

// ---------------- K5: GCN mixed = a @ t_x  (per (b,t): [2048,2048]x[2048,128]) ----------------
// m97-structure: async global_load_lds (width=16) with pre-swizzled source.
__global__ __launch_bounds__(256) void gcn_gemm(
        const u16* __restrict__ abf, const u16* __restrict__ txT, u16* __restrict__ mixed) {
    int bt = blockIdx.x >> 4;
    int n0 = (blockIdx.x & 15) * 128;
    __shared__ u16 sA[128 * 64];
    __shared__ u16 sB[128 * 64];
    int tid = threadIdx.x, lane = tid & 63, ln15 = lane & 15, g16 = lane >> 4, wid = tid >> 6;
    int wm = (wid >> 1) * 64, wn = (wid & 1) * 64;
    f32x4 acc[4][4];
    zero_acc(acc);
    const u16* aRow = abf + (size_t)n0 * 2048;
    const u16* bRow = txT + (size_t)bt * 128 * 2048;
    for (int k0 = 0; k0 < 2048; k0 += 64) {
        __syncthreads();                 // previous compute's LDS reads done
        #pragma unroll
        for (int i = 0; i < 4; ++i) stage_async64(sA, aRow + k0, wid * 4 + i, lane);
        #pragma unroll
        for (int i = 0; i < 4; ++i) stage_async64(sB, bRow + k0, wid * 4 + i, lane);
        __syncthreads();                 // compiler drains vmcnt(0) before barrier
        #pragma unroll
        for (int ks = 0; ks < 2; ++ks)
            gemm_step64<64, 64>(sA, sB, wm, wn, ks * 64 + g16 * 16, acc, ln15);
    }
    u16* out = mixed + ((size_t)(bt * 2048 + n0)) * 128;
    #pragma unroll
    for (int i = 0; i < 4; ++i)
        #pragma unroll
        for (int j = 0; j < 4; ++j)
            #pragma unroll
            for (int r = 0; r < 4; ++r) {
                int row = wm + i * 16 + g16 * 4 + r;
                int col = wn + j * 16 + ln15;
                out[(size_t)row * 128 + col] = f2b(acc[i][j][r]);
            }
}

// ---------------- K6: gcn_fc1 + alpha-mix + gcn_mlp + residual + norm2 + router + top2 ----------------
__global__ __launch_bounds__(256) void fused_gcn_router(
        const u16* __restrict__ mixed, const u16* __restrict__ txn,
        const float* __restrict__ x,
        const u16* __restrict__ W1, const u16* __restrict__ W2,
        const float* __restrict__ bias2, const float* __restrict__ n2w,
        const float* __restrict__ gatew,
        float* __restrict__ outx, float* __restrict__ outlog,
        u16* __restrict__ x2n,
        int* __restrict__ lists, float* __restrict__ listw, int* __restrict__ cnts) {
    int tok0 = blockIdx.x * 128;
    __shared__ char LB[65536];
    __shared__ float sGate[1024];
    __shared__ float sN2[128];
    __shared__ float sBias[128];
    __shared__ float sLog[1024];
    __shared__ float sPart[256];
    __shared__ float sScale[128];
    __shared__ int sBCnt[8];
    __shared__ int sGBase[8];
    u16* sM = (u16*)LB;
    u16* sW = (u16*)(LB + 32768);
    float* sXn = (float*)LB;           // overlay, used after GEMM2
    int tid = threadIdx.x, lane = tid & 63, ln15 = lane & 15, g16 = lane >> 4, wid = tid >> 6;
    int wm = (wid >> 1) * 64, wn = (wid & 1) * 64;
    stage_bf16<128>(sM, mixed + (size_t)tok0 * 128, 128, 128, tid, 256);
    stage_bf16<128>(sW, W1, 128, 128, tid, 256);
    for (int i = tid; i < 1024; i += 256) sGate[i] = gatew[i];
    if (tid < 128) { sN2[tid] = n2w[tid]; sBias[tid] = bias2[tid]; }
    if (tid < 8) sBCnt[tid] = 0;
    __syncthreads();
    f32x4 acc[4][4];
    zero_acc(acc);
    #pragma unroll
    for (int ks = 0; ks < 4; ++ks)
        gemm_step64<128, 128>(sM, sW, wm, wn, ks * 64 + g16 * 16, acc, ln15);
    __syncthreads();
    // mixed & W1 dead: stage t_x over sM, W2 over sW
    stage_bf16<128>(sM, txn + (size_t)tok0 * 128, 128, 128, tid, 256);
    stage_bf16<128>(sW, W2, 128, 128, tid, 256);
    __syncthreads();
    // in-place alpha-mix: h = 0.05*t_x + 0.95*gcn_out (per-thread bijective cells)
    #pragma unroll
    for (int i = 0; i < 4; ++i)
        #pragma unroll
        for (int j = 0; j < 4; ++j)
            #pragma unroll
            for (int r = 0; r < 4; ++r) {
                int row = wm + i * 16 + g16 * 4 + r;
                int col = wn + j * 16 + ln15;
                float tv = b2f(lds_us<128>(sM, row, col));
                lds_store_us<128>(sM, row, col, f2b(0.05f * tv + 0.95f * acc[i][j][r]));
            }
    __syncthreads();
    zero_acc(acc);
    #pragma unroll
    for (int ks = 0; ks < 4; ++ks)
        gemm_step64<128, 128>(sM, sW, wm, wn, ks * 64 + g16 * 16, acc, ln15);
    // epilogue in regs: xv = x + ho + bias; write outx; keep xv in acc
    #pragma unroll
    for (int i = 0; i < 4; ++i)
        #pragma unroll
        for (int j = 0; j < 4; ++j)
            #pragma unroll
            for (int r = 0; r < 4; ++r) {
                int row = wm + i * 16 + g16 * 4 + r;
                int col = wn + j * 16 + ln15;
                float xv = x[(size_t)(tok0 + row) * 128 + col] + acc[i][j][r] + sBias[col];
                outx[(size_t)(tok0 + row) * 128 + col] = xv;
                acc[i][j][r] = xv;
            }
    // per-row sum of squares: reduce over 16 lanes (cols of this wave) -> sPart[row][wavehalf]
    #pragma unroll
    for (int i = 0; i < 4; ++i)
        #pragma unroll
        for (int r = 0; r < 4; ++r) {
            float s = 0.f;
            #pragma unroll
            for (int j = 0; j < 4; ++j) s += acc[i][j][r] * acc[i][j][r];
            s += __shfl_xor(s, 1); s += __shfl_xor(s, 2);
            s += __shfl_xor(s, 4); s += __shfl_xor(s, 8);
            if (ln15 == 0) sPart[(wm + i * 16 + g16 * 4 + r) * 2 + (wid & 1)] = s;
        }
    __syncthreads();   // also guarantees GEMM2's LDS reads are done before sXn overlay
    if (tid < 128)
        sScale[tid] = rsqrtf((sPart[tid * 2] + sPart[tid * 2 + 1]) * (1.f / 128.f) + 1e-6f);
    __syncthreads();
    // write f32 normalized tile into the 64KB overlay
    #pragma unroll
    for (int i = 0; i < 4; ++i)
        #pragma unroll
        for (int j = 0; j < 4; ++j)
            #pragma unroll
            for (int r = 0; r < 4; ++r) {
                int row = wm + i * 16 + g16 * 4 + r;
                int col = wn + j * 16 + ln15;
                sXn[row * 128 + col] = acc[i][j][r] * sScale[row] * sN2[col];
            }
    __syncthreads();
    {   // router logits (2 threads per row x 4 experts each); rotate c by r to dodge banks
        int r = tid >> 1, e0 = (tid & 1) * 4;
        float a0 = 0, a1 = 0, a2 = 0, a3 = 0;
        for (int cc = 0; cc < 128; ++cc) {
            int c = (cc + r) & 127;
            float v = sXn[r * 128 + c];
            a0 += v * sGate[(e0 + 0) * 128 + c];
            a1 += v * sGate[(e0 + 1) * 128 + c];
            a2 += v * sGate[(e0 + 2) * 128 + c];
            a3 += v * sGate[(e0 + 3) * 128 + c];
        }
        int rb = r * 8 + e0;
        sLog[rb + 0] = a0; sLog[rb + 1] = a1; sLog[rb + 2] = a2; sLog[rb + 3] = a3;
        size_t ob = (size_t)(tok0 + r) * 8 + e0;
        outlog[ob + 0] = a0; outlog[ob + 1] = a1; outlog[ob + 2] = a2; outlog[ob + 3] = a3;
    }
    // x2n store (bf16, vectorized) straight from the f32 overlay
    for (int cc = tid; cc < 2048; cc += 256) {
        int r = cc >> 4, c0 = (cc & 15) * 8;
        union { u32x4 v; u16 us[8]; } u;
        #pragma unroll
        for (int jj = 0; jj < 8; ++jj) u.us[jj] = f2b(sXn[r * 128 + c0 + jj]);
        *(u32x4*)(x2n + (size_t)(tok0 + r) * 128 + c0) = u.v;
    }
    __syncthreads();
    // top-2 with BLOCK-AGGREGATED list build (8 global atomics per block)
    // list payload = tok*2 + slot  (slot 0 = top-1 entry, 1 = top-2 entry)
    int e1 = 0, e2 = 0, le1 = 0, le2 = 0;
    float w1v = 0.f, w2v = 0.f;
    if (tid < 128) {
        int r = tid;
        float l[8];
        #pragma unroll
        for (int e = 0; e < 8; ++e) l[e] = sLog[r * 8 + e];
        float m = l[0];
        #pragma unroll
        for (int e = 1; e < 8; ++e) m = fmaxf(m, l[e]);
        float ex[8]; float s = 0.f;
        #pragma unroll
        for (int e = 0; e < 8; ++e) { ex[e] = __expf(l[e] - m); s += ex[e]; }
        float inv = 1.f / s;
        float b1v = ex[0]; e1 = 0;
        #pragma unroll
        for (int e = 1; e < 8; ++e) if (ex[e] > b1v) { b1v = ex[e]; e1 = e; }
        e2 = (e1 == 0) ? 1 : 0; float b2v = ex[e2];
        #pragma unroll
        for (int e = 0; e < 8; ++e) if (e != e1 && ex[e] > b2v) { b2v = ex[e]; e2 = e; }
        w1v = b1v * inv; w2v = b2v * inv;
        le1 = atomicAdd(&sBCnt[e1], 1);
        le2 = atomicAdd(&sBCnt[e2], 1);
    }
    __syncthreads();
    if (tid < 8) sGBase[tid] = atomicAdd(&cnts[tid], sBCnt[tid]);
    __syncthreads();
    if (tid < 128) {
        int tok = tok0 + tid;
        int p1 = sGBase[e1] + le1;
        lists[(size_t)e1 * TOK + p1] = tok * 2 + 0; listw[(size_t)e1 * TOK + p1] = w1v;
        int p2 = sGBase[e2] + le2;
        lists[(size_t)e2 * TOK + p2] = tok * 2 + 1; listw[(size_t)e2 * TOK + p2] = w2v;
    }
}

// ---------------- K7: sparse expert swiglu, dbuf + reg-prefetch (T14), padded W2/sH ----------------
__global__ __launch_bounds__(256, 2) void moe_expert(
        const u16* __restrict__ x2n, const int* __restrict__ lists,
        const float* __restrict__ listw, const int* __restrict__ cnts,
        const u16* __restrict__ bw1, const u16* __restrict__ bw2,
        const u16* __restrict__ bw3, u16* __restrict__ slotOut) {
    int e = blockIdx.y;
    int base = blockIdx.x * 128;
    int cnt = cnts[e];
    if (base >= cnt) return;
    int valid = min(128, cnt - base);
    const int* lst = lists + (size_t)e * TOK + base;
    const float* lw = listw + (size_t)e * TOK + base;
    __shared__ u16 sX2[128 * 128];     // 32KB; reused as weight buffer B after av preload
    __shared__ u16 sBufA[13312];       // 26624B weight buffer A
    __shared__ u16 sH[5120];           // 128 rows x 80B
    __shared__ float sCoef[128];
    __shared__ int sTok[128];
    u16* bufB = sX2;
    int tid = threadIdx.x, lane = tid & 63, ln15 = lane & 15, g16 = lane >> 4, wid = tid >> 6;
    if (tid < 128) {
        int t = (tid < valid) ? lst[tid] : -1;
        sTok[tid] = t;
        sCoef[tid] = (tid < valid) ? lw[tid] : 0.f;
    }
    const u16* w1base = bw1 + (size_t)e * (256 * 128);
    const u16* w3base = bw3 + (size_t)e * (256 * 128);
    const u16* w2base = bw2 + (size_t)e * (128 * 256);
    // chunk 0 -> bufA (load now, write now; overlaps sTok barrier wait)
    u32x4 pf0[6];
    prefetch_regs(pf0, w1base, w3base, w2base, 256, tid);
    __syncthreads();                    // sTok/sCoef visible
    // gather x2 -> sX2 (swizzled)
    for (int i = tid; i < 2048; i += 256) {
        int r = i >> 4, cc = i & 15;
        int t = sTok[r];
        u32x4 v = {0, 0, 0, 0};
        if (t >= 0) v = *(const u32x4*)(x2n + (size_t)(t >> 1) * 128 + cc * 8);
        *(u32x4*)((char*)sX2 + r * 256 + ((cc * 16) ^ ((r & 7) << 4))) = v;
    }
    write_chunk(sBufA, pf0, tid);
    __syncthreads();
    // preload x2 fragments; sX2 dead afterwards
    bf16x8 av[2][4];
    #pragma unroll
    for (int mf = 0; mf < 2; ++mf)
        #pragma unroll
        for (int ks = 0; ks < 4; ++ks)
            av[mf][ks] = frag_ld<128>(sX2, wid * 32 + mf * 16 + ln15, ks * 64 + g16 * 16);
    f32x4 aout[2][8];
    f32x4 z = {0.f, 0.f, 0.f, 0.f};
    #pragma unroll
    for (int mf = 0; mf < 2; ++mf)
        #pragma unroll
        for (int nf = 0; nf < 8; ++nf) aout[mf][nf] = z;
    __syncthreads();                    // all av reads done before bufB (sX2) overwritten
    for (int ic = 0; ic < 8; ++ic) {
        u16* cur = (ic & 1) ? bufB : sBufA;
        u16* alt = (ic & 1) ? sBufA : bufB;
        u32x4 pf[6];
        bool hasNext = (ic + 1 < 8);
        if (hasNext)
            prefetch_regs(pf, w1base + (ic + 1) * 4096, w3base + (ic + 1) * 4096,
                          w2base + (ic + 1) * 32, 256, tid);
        swiglu_chunk(cur, sH, av, aout, wid, g16, ln15);
        if (hasNext) write_chunk(alt, pf, tid);
        __syncthreads();               // drains vmcnt+lgkm; next chunk resident; cur free
    }
    #pragma unroll
    for (int mf = 0; mf < 2; ++mf)
        #pragma unroll
        for (int nf = 0; nf < 8; ++nf)
            #pragma unroll
            for (int r = 0; r < 4; ++r) {
                int row = wid * 32 + mf * 16 + g16 * 4 + r;
                if (row < valid) {
                    int col = nf * 16 + ln15;
                    slotOut[(size_t)sTok[row] * 128 + col] = f2b(sCoef[row] * aout[mf][nf][r]);
                }
            }
}

// ---------------- K8: shared expert swiglu, dbuf + reg-prefetch, padded, + gate + combine ----------------
__global__ __launch_bounds__(256, 2) void moe_shared(
        const u16* __restrict__ x2n, const u16* __restrict__ bw1,
        const u16* __restrict__ bw2, const u16* __restrict__ bw3,
        const float* __restrict__ sgw, const u16* __restrict__ slotOut,
        float* __restrict__ outx) {
    int tok0 = blockIdx.x * 128;
    __shared__ u16 sX2[128 * 128];     // 32KB; reused as weight buffer B
    __shared__ u16 sBufA[13312];       // 26624B
    __shared__ u16 sH[5120];           // 128 x 80B
    __shared__ float sGv[128];
    __shared__ float sSG[128];
    u16* bufB = sX2;
    int tid = threadIdx.x, lane = tid & 63, ln15 = lane & 15, g16 = lane >> 4, wid = tid >> 6;
    u32x4 pf0[6];
    prefetch_regs(pf0, bw1, bw3, bw2, 512, tid);
    stage_bf16<128>(sX2, x2n + (size_t)tok0 * 128, 128, 128, tid, 256);
    write_chunk(sBufA, pf0, tid);
    if (tid < 128) sSG[tid] = sgw[tid];
    __syncthreads();
    // sigmoid gate dot + x2 fragment preload (sX2 dead afterwards)
    if (tid < 128) {
        float d = 0.f;
        for (int cc = 0; cc < 128; ++cc) {
            int c = (cc + tid) & 127;
            d += b2f(lds_us<128>(sX2, tid, c)) * sSG[c];
        }
        sGv[tid] = 1.f / (1.f + __expf(-d));
    }
    bf16x8 av[2][4];
    #pragma unroll
    for (int mf = 0; mf < 2; ++mf)
        #pragma unroll
        for (int ks = 0; ks < 4; ++ks)
            av[mf][ks] = frag_ld<128>(sX2, wid * 32 + mf * 16 + ln15, ks * 64 + g16 * 16);
    f32x4 aout[2][8];
    f32x4 z = {0.f, 0.f, 0.f, 0.f};
    #pragma unroll
    for (int mf = 0; mf < 2; ++mf)
        #pragma unroll
        for (int nf = 0; nf < 8; ++nf) aout[mf][nf] = z;
    __syncthreads();                    // all sX2 reads done before bufB overwritten
    for (int ic = 0; ic < 16; ++ic) {
        u16* cur = (ic & 1) ? bufB : sBufA;
        u16* alt = (ic & 1) ? sBufA : bufB;
        u32x4 pf[6];
        bool hasNext = (ic + 1 < 16);
        if (hasNext)
            prefetch_regs(pf, bw1 + (ic + 1) * 4096, bw3 + (ic + 1) * 4096,
                          bw2 + (ic + 1) * 32, 512, tid);
        swiglu_chunk(cur, sH, av, aout, wid, g16, ln15);
        if (hasNext) write_chunk(alt, pf, tid);
        __syncthreads();
    }
    #pragma unroll
    for (int mf = 0; mf < 2; ++mf)
        #pragma unroll
        for (int nf = 0; nf < 8; ++nf)
            #pragma unroll
            for (int r = 0; r < 4; ++r) {
                int row = wid * 32 + mf * 16 + g16 * 4 + r;
                int col = nf * 16 + ln15;
                size_t t = (size_t)(tok0 + row);
                float fc = b2f(slotOut[(t * 2 + 0) * 128 + col])
                         + b2f(slotOut[(t * 2 + 1) * 128 + col]);
                size_t idx = t * 128 + col;
                outx[idx] = outx[idx] + fc + sGv[row] * aout[mf][nf][r];
            }
}

// ---------------- host launcher ----------------
// workspace layout (bytes)
#define SZTD  ((size_t)TOK * 128 * 2)          // 50331648, one bf16 [Tok,128] buffer
#define OFF_XN   ((size_t)0)                   // x_n -> t_x_n
#define OFF_KN   (SZTD)                        // k_n -> mixed
#define OFF_Q    (SZTD * 2)                    // q -> t_xT -> x2n
#define OFF_KP   (SZTD * 3)                    // kp ; later slotOut bf16 [2*TOK][128] spans KP..KP+SZTD*2
#define OFF_VP   (SZTD * 4)                    // vp
#define OFF_ABF  (SZTD * 5)                    // a bf16 [2048,2048] = 8388608
#define OFF_LW   (OFF_ABF + 8388608)           // listw f32 [8*TOK]
#define OFF_LIST (OFF_LW + (size_t)8 * TOK * 4)
#define OFF_CNT  (OFF_LIST + (size_t)8 * TOK * 4)
#define OFF_ARENA (OFF_CNT + 128)              // bf16 weights arena, 1064960 elems

extern "C" void kernel_launch(void* const* d_in, const int* in_sizes, int n_in,
                              void* d_out, int out_size, void* d_ws, size_t ws_size,
                              hipStream_t stream) {
    (void)in_sizes; (void)n_in; (void)out_size; (void)ws_size;
    const float* x    = (const float*)d_in[0];
    const float* k    = (const float*)d_in[1];
    // d_in[2] (v) is unused by the reference
    const float* adj  = (const float*)d_in[3];
    const float* Wq   = (const float*)d_in[4];
    const float* bq   = (const float*)d_in[5];
    const float* Wk   = (const float*)d_in[6];
    const float* bk   = (const float*)d_in[7];
    const float* Wv   = (const float*)d_in[8];
    const float* bv   = (const float*)d_in[9];
    const float* ntw  = (const float*)d_in[10];
    const float* gfc1 = (const float*)d_in[11];
    const float* gmlp = (const float*)d_in[12];
    const float* gmlpb= (const float*)d_in[13];
    const float* n1w  = (const float*)d_in[14];
    const float* n2w  = (const float*)d_in[15];
    const float* gatew= (const float*)d_in[16];
    const float* ew1  = (const float*)d_in[17];
    const float* ew2  = (const float*)d_in[18];
    const float* ew3  = (const float*)d_in[19];
    const float* sw1  = (const float*)d_in[20];
    const float* sw2  = (const float*)d_in[21];
    const float* sw3  = (const float*)d_in[22];
    const float* sgw  = (const float*)d_in[23];

    char* ws = (char*)d_ws;
    u16*  xn   = (u16*)(ws + OFF_XN);
    u16*  kn   = (u16*)(ws + OFF_KN);
    u16*  qb   = (u16*)(ws + OFF_Q);
    u16*  kpb  = (u16*)(ws + OFF_KP);
    u16*  vpb  = (u16*)(ws + OFF_VP);
    u16*  slotOut = (u16*)(ws + OFF_KP);      // overlaps kp+vp (dead after attention)
    u16*  abf  = (u16*)(ws + OFF_ABF);
    float* lw  = (float*)(ws + OFF_LW);
    int*  lst  = (int*)(ws + OFF_LIST);
    int*  cnts = (int*)(ws + OFF_CNT);
    u16*  arena = (u16*)(ws + OFF_ARENA);
    u16*  bWq = arena;
    u16*  bWk = arena + 16384;
    u16*  bWv = arena + 32768;
    u16*  bG1 = arena + 49152;
    u16*  bG2 = arena + 65536;
    u16*  bE1 = arena + 81920;
    u16*  bE2 = arena + 344064;
    u16*  bE3 = arena + 606208;
    u16*  bS1 = arena + 868352;
    u16*  bS2 = arena + 933888;
    u16*  bS3 = arena + 999424;
    float* outx   = (float*)d_out;
    float* outlog = outx + (size_t)TOK * 128;

    preconvert<<<1040, 256, 0, stream>>>(Wq, Wk, Wv, gfc1, gmlp, ew1, ew2, ew3,
                                         sw1, sw2, sw3, arena, cnts);
    rmsnorm_pair<<<98304, 256, 0, stream>>>(x, k, n1w, xn, kn);
    proj128<<<1536, 256, 0, stream>>>(xn, bWq, bq, qb);
    proj128<<<1536, 256, 0, stream>>>(kn, bWk, bk, kpb);
    proj128<<<1536, 256, 0, stream>>>(kn, bWv, bv, vpb);
    attn_kernel<<<8192, 256, 0, stream>>>(qb, kpb, vpb, ntw, xn /* t_x_n */);
    adj_norm<<<2048, 256, 0, stream>>>(adj, abf);
    transpose_k<<<3072, 256, 0, stream>>>(xn, qb /* t_xT */);
    gcn_gemm<<<1536, 256, 0, stream>>>(abf, qb, kn /* mixed */);
    fused_gcn_router<<<1536, 256, 0, stream>>>(kn, xn, x, bG1, bG2, gmlpb, n2w, gatew,
                                               outx, outlog, qb /* x2n */, lst, lw, cnts);
    moe_expert<<<dim3(1536, 8), 256, 0, stream>>>(qb, lst, lw, cnts, bE1, bE2, bE3, slotOut);
    moe_shared<<<1536, 256, 0, stream>>>(qb, bS1, bS2, bS3, sgw, slotOut, outx);
}

// Round 9
// 751.011 us; speedup vs baseline: 1.4835x; 1.0361x over previous
//
#include <hip/hip_runtime.h>

// ---------------- problem constants ----------------
#define BB 4
#define TT 24
#define NN 2048
#define DD 128
#define HH 4
#define HD 32
#define TOK 196608          // BB*TT*NN
#define EE 8
#define MINTER 256
#define INTER 512

typedef unsigned short u16;
typedef __attribute__((ext_vector_type(8))) short  bf16x8;
typedef __attribute__((ext_vector_type(4))) float  f32x4;
typedef __attribute__((ext_vector_type(4))) unsigned int u32x4;

#define MFMA(a,b,c) __builtin_amdgcn_mfma_f32_16x16x32_bf16((a),(b),(c),0,0,0)
#define AS(n) __attribute__((address_space(n)))

// ---------------- small helpers ----------------
static __device__ __forceinline__ u16 f2b(float f) {
    union { float f; unsigned u; } v; v.f = f;
    unsigned r = v.u + 0x7FFFu + ((v.u >> 16) & 1u);
    return (u16)(r >> 16);
}
static __device__ __forceinline__ float b2f(u16 b) {
    union { unsigned u; float f; } v; v.u = ((unsigned)b) << 16;
    return v.f;
}
static __device__ __forceinline__ float silu_mul(float u, float v) {
    return u * __builtin_amdgcn_rcpf(1.f + __expf(-u)) * v;
}

// LDS tile helpers.  Tiles are [rows][C] bf16, row stride C*2 bytes, with a
// 16B-chunk XOR swizzle: chunk cc of row r lives at byte r*C*2 + ((cc*16) ^ ((r&mask)<<4)).
template<int C>
static __device__ __forceinline__ bf16x8 frag_ld(const u16* s, int row, int kbyte) {
    constexpr int mask = ((C/8) < 8 ? (C/8) : 8) - 1;
    int byte = row * (C * 2) + (kbyte ^ ((row & mask) << 4));
    return *(const bf16x8*)((const char*)s + byte);
}
template<int C>
static __device__ __forceinline__ u16 lds_us(const u16* s, int r, int c) {
    constexpr int mask = ((C/8) < 8 ? (C/8) : 8) - 1;
    int byte = r * (C * 2) + ((((c >> 3) << 4) ^ ((r & mask) << 4))) + ((c & 7) << 1);
    return *(const u16*)((const char*)s + byte);
}
template<int C>
static __device__ __forceinline__ void lds_store_us(u16* s, int r, int c, u16 v) {
    constexpr int mask = ((C/8) < 8 ? (C/8) : 8) - 1;
    int byte = r * (C * 2) + ((((c >> 3) << 4) ^ ((r & mask) << 4))) + ((c & 7) << 1);
    *(u16*)((char*)s + byte) = v;
}
// 80B-padded row stride (period-8 bank pattern, conflict-free for 16B reads)
static __device__ __forceinline__ bf16x8 frag_ld_p80(const u16* s, int row, int kbyte) {
    return *(const bf16x8*)((const char*)s + row * 80 + kbyte);
}
static __device__ __forceinline__ void sh_store_p80(u16* s, int r, int c, u16 v) {
    *(u16*)((char*)s + r * 80 + c * 2) = v;
}
// stage bf16 global -> swizzled LDS tile (reg path)
template<int C>
static __device__ __forceinline__ void stage_bf16(u16* s, const u16* g, int gstride,
                                                  int rows, int tid, int nthr) {
    constexpr int cpr = C / 8;
    constexpr int mask = (cpr < 8 ? cpr : 8) - 1;
    for (int i = tid; i < rows * cpr; i += nthr) {
        int r = i / cpr, cc = i - r * cpr;
        u32x4 v = *(const u32x4*)(g + (size_t)r * gstride + cc * 8);
        *(u32x4*)((char*)s + r * (C * 2) + ((cc * 16) ^ ((r & mask) << 4))) = v;
    }
}
// async stage for a [128][64] bf16 tile from row-major global (stride 2048):
// LDS linear dest (wave base + lane*16), PRE-SWIZZLED global source chunk.
static __device__ __forceinline__ void stage_async64(u16* s, const u16* g, int wi, int lane) {
    int slot = wi * 64 + lane;            // 16B-chunk index in [0,1024)
    int r = slot >> 3, c = slot & 7;
    const u16* src = g + r * 2048 + ((c ^ (r & 7)) << 3);
    __builtin_amdgcn_global_load_lds((const AS(1) void*)src,
                                     (AS(3) void*)(s + wi * 512), 16, 0, 0);
}
// async stage of a pre-built 26624B weight-chunk image: linear copy.
// 26 slots of 1024B; wave w handles slots w, w+4, ...
static __device__ __forceinline__ void stage_img(u16* buf, const u16* img, int wid, int lane) {
    #pragma unroll
    for (int t = 0; t < 7; ++t) {
        int wi = wid + t * 4;
        if (wi < 26)
            __builtin_amdgcn_global_load_lds((const AS(1) void*)(img + wi * 512 + lane * 8),
                                             (AS(3) void*)(buf + wi * 512), 16, 0, 0);
    }
}
static __device__ __forceinline__ void zero_acc(f32x4 acc[4][4]) {
    f32x4 z = {0.f, 0.f, 0.f, 0.f};
    #pragma unroll
    for (int i = 0; i < 4; ++i)
        #pragma unroll
        for (int j = 0; j < 4; ++j) acc[i][j] = z;
}
// one K-step (32) of a 64x64 wave tile: 4 A frags x 4 B frags -> 16 MFMA
template<int CA, int CB>
static __device__ __forceinline__ void gemm_step64(const u16* sA, const u16* sB,
        int arow0, int brow0, int kbyte, f32x4 acc[4][4], int ln15) {
    bf16x8 a[4], b[4];
    #pragma unroll
    for (int i = 0; i < 4; ++i) a[i] = frag_ld<CA>(sA, arow0 + i * 16 + ln15, kbyte);
    #pragma unroll
    for (int j = 0; j < 4; ++j) b[j] = frag_ld<CB>(sB, brow0 + j * 16 + ln15, kbyte);
    #pragma unroll
    for (int i = 0; i < 4; ++i)
        #pragma unroll
        for (int j = 0; j < 4; ++j)
            acc[i][j] = MFMA(a[i], b[j], acc[i][j]);
}

// one swiglu inter-chunk (32 wide) on a staged image buf:
// W1c [32][128] swz @0, W3c swz @4096 (u16), W2c [128] 80B rows @8192 (u16)
static __device__ __forceinline__ void swiglu_chunk(const u16* buf, u16* sH,
        const bf16x8 av[2][4], f32x4 aout[2][8],
        int wid, int g16, int ln15) {
    const u16* W1c = buf;
    const u16* W3c = buf + 4096;
    const u16* W2c = buf + 8192;
    f32x4 z = {0.f, 0.f, 0.f, 0.f};
    f32x4 a1[2][2], a3[2][2];
    #pragma unroll
    for (int mf = 0; mf < 2; ++mf)
        #pragma unroll
        for (int nf = 0; nf < 2; ++nf) { a1[mf][nf] = z; a3[mf][nf] = z; }
    #pragma unroll
    for (int ks = 0; ks < 4; ++ks) {
        int kb = ks * 64 + g16 * 16;
        #pragma unroll
        for (int nf = 0; nf < 2; ++nf) {
            bf16x8 b1 = frag_ld<128>(W1c, nf * 16 + ln15, kb);
            bf16x8 b3 = frag_ld<128>(W3c, nf * 16 + ln15, kb);
            a1[0][nf] = MFMA(av[0][ks], b1, a1[0][nf]);
            a1[1][nf] = MFMA(av[1][ks], b1, a1[1][nf]);
            a3[0][nf] = MFMA(av[0][ks], b3, a3[0][nf]);
            a3[1][nf] = MFMA(av[1][ks], b3, a3[1][nf]);
        }
    }
    #pragma unroll
    for (int mf = 0; mf < 2; ++mf)
        #pragma unroll
        for (int nf = 0; nf < 2; ++nf)
            #pragma unroll
            for (int r = 0; r < 4; ++r) {
                int row = wid * 32 + mf * 16 + g16 * 4 + r;
                int col = nf * 16 + ln15;
                sh_store_p80(sH, row, col, f2b(silu_mul(a1[mf][nf][r], a3[mf][nf][r])));
            }
    // sH rows are wave-private: wave w writes & reads only rows w*32..w*32+31
    asm volatile("s_waitcnt lgkmcnt(0)" ::: "memory");
    __builtin_amdgcn_sched_barrier(0);
    {
        int kb = g16 * 16;
        bf16x8 ah0 = frag_ld_p80(sH, wid * 32 + ln15, kb);
        bf16x8 ah1 = frag_ld_p80(sH, wid * 32 + 16 + ln15, kb);
        #pragma unroll
        for (int nf = 0; nf < 8; ++nf) {
            bf16x8 bw = frag_ld_p80(W2c, nf * 16 + ln15, kb);
            aout[0][nf] = MFMA(ah0, bw, aout[0][nf]);
            aout[1][nf] = MFMA(ah1, bw, aout[1][nf]);
        }
    }
}

// ---------------- K0: preconvert weights -> bf16 arena (dense mats + MoE chunk IMAGES) ----
// arena u16 offsets: Wq 0, Wk 16384, Wv 32768, g1 49152, g2 65536,
// expert images @81920 (64 images x 13312), shared images @933888 (16 x 13312).
// image: [W1c 32x128 swz | W3c 32x128 swz | W2c 128 rows x 80B padded]
__global__ __launch_bounds__(256) void preconvert(
        const float* __restrict__ Wq, const float* __restrict__ Wk,
        const float* __restrict__ Wv, const float* __restrict__ g1,
        const float* __restrict__ g2,
        const float* __restrict__ e1, const float* __restrict__ e2,
        const float* __restrict__ e3,
        const float* __restrict__ s1, const float* __restrict__ s2,
        const float* __restrict__ s3,
        u16* __restrict__ arena, int* __restrict__ cnts) {
    int idx = blockIdx.x * 256 + threadIdx.x;
    if (blockIdx.x == 0 && threadIdx.x < 8) cnts[threadIdx.x] = 0;
    if (idx < 20480) {      // dense mats, 4-elem granularity
        int s = idx >> 12, rel = idx & 4095;
        const float* src = (s == 0) ? Wq : (s == 1) ? Wk : (s == 2) ? Wv : (s == 3) ? g1 : g2;
        const float4 v = *(const float4*)(src + (size_t)rel * 4);
        union { unsigned long long q; u16 us[4]; } o;
        o.us[0] = f2b(v.x); o.us[1] = f2b(v.y); o.us[2] = f2b(v.z); o.us[3] = f2b(v.w);
        *(unsigned long long*)(arena + (size_t)idx * 4) = o.q;
        return;
    }
    int p = idx - 20480;                 // image 16B-chunk index
    if (p >= 133120) return;             // 64*1664 + 16*1664
    const float *w1s, *w3s, *w2s_; int w2stride, ic;
    u16* img;
    if (p < 106496) {                    // expert images
        int imgIdx = p / 1664;
        p -= imgIdx * 1664;
        int e = imgIdx >> 3; ic = imgIdx & 7;
        w1s = e1 + (size_t)e * 32768;    // [256][128]
        w3s = e3 + (size_t)e * 32768;
        w2s_ = e2 + (size_t)e * 32768;   // [128][256]
        w2stride = 256;
        img = arena + 81920 + (size_t)imgIdx * 13312;
    } else {
        int q = p - 106496;
        int imgIdx = q / 1664; ic = imgIdx;
        p = q - imgIdx * 1664;
        w1s = s1; w3s = s3; w2s_ = s2; w2stride = 512;
        img = arena + 933888 + (size_t)imgIdx * 13312;
    }
    const float* src;
    if (p < 1024) {                      // W1/W3 swizzled regions
        const float* wsrc = (p < 512) ? w1s : w3s;
        int pp = p & 511;
        int r = pp >> 4, chq = pp & 15;
        int cc = chq ^ (r & 7);
        src = wsrc + (size_t)(ic * 32 + r) * 128 + cc * 8;
    } else {                             // W2 padded region
        int q = p - 1024;
        int r = q / 5, cc = q - r * 5;
        if (cc == 4) {                   // pad chunk
            u32x4 zv = {0, 0, 0, 0};
            *(u32x4*)(img + (size_t)p * 8) = zv;
            return;
        }
        src = w2s_ + (size_t)r * w2stride + ic * 32 + cc * 8;
    }
    union { u32x4 v; u16 us[8]; } o;
    #pragma unroll
    for (int j = 0; j < 8; ++j) o.us[j] = f2b(src[j]);
    *(u32x4*)(img + (size_t)p * 8) = o.v;
}

// ---------------- K1: rmsnorm of x and k -> bf16 ----------------
__global__ __launch_bounds__(256) void rmsnorm_pair(
        const float* __restrict__ x, const float* __restrict__ k,
        const float* __restrict__ w, u16* __restrict__ xn, u16* __restrict__ kn) {
    int row = blockIdx.x * 4 + (threadIdx.x >> 6);
    int lane = threadIdx.x & 63;
    const float* in; u16* out;
    if (row < TOK) { in = x + (size_t)row * 128; out = xn + (size_t)row * 128; }
    else           { in = k + (size_t)(row - TOK) * 128; out = kn + (size_t)(row - TOK) * 128; }
    float2 v = *(const float2*)(in + lane * 2);
    float ss = v.x * v.x + v.y * v.y;
    #pragma unroll
    for (int o = 32; o > 0; o >>= 1) ss += __shfl_xor(ss, o);
    float sc = rsqrtf(ss * (1.f / 128.f) + 1e-6f);
    float2 wv = *(const float2*)(w + lane * 2);
    unsigned pack = ((unsigned)f2b(v.y * sc * wv.y) << 16) | (unsigned)f2b(v.x * sc * wv.x);
    *(unsigned*)(out + lane * 2) = pack;
}

// ---------------- K2: [Tok,128] @ W[128,128]^T + bias -> bf16 (bf16 weights) ----------------
__global__ __launch_bounds__(256) void proj128(
        const u16* __restrict__ in, const u16* __restrict__ W,
        const float* __restrict__ bias, u16* __restrict__ out) {
    int tok0 = blockIdx.x * 128;
    __shared__ u16 sA[128 * 128];
    __shared__ u16 sW[128 * 128];
    int tid = threadIdx.x, lane = tid & 63, ln15 = lane & 15, g16 = lane >> 4, wid = tid >> 6;
    int wm = (wid >> 1) * 64, wn = (wid & 1) * 64;
    stage_bf16<128>(sA, in + (size_t)tok0 * 128, 128, 128, tid, 256);
    stage_bf16<128>(sW, W, 128, 128, tid, 256);
    __syncthreads();
    f32x4 acc[4][4];
    zero_acc(acc);
    #pragma unroll
    for (int ks = 0; ks < 4; ++ks)
        gemm_step64<128, 128>(sA, sW, wm, wn, ks * 64 + g16 * 16, acc, ln15);
    #pragma unroll
    for (int j = 0; j < 4; ++j) {
        int col = wn + j * 16 + ln15;
        float bv = bias[col];
        #pragma unroll
        for (int i = 0; i < 4; ++i)
            #pragma unroll
            for (int r = 0; r < 4; ++r) {
                int row = wm + i * 16 + g16 * 4 + r;
                out[(size_t)(tok0 + row) * 128 + col] = f2b(acc[i][j][r] + bv);
            }
    }
}

// ---------------- K3: attention over T per (b,n), all 4 heads, fused rmsnorm ----------------
__global__ __launch_bounds__(256) void attn_kernel(
        const u16* __restrict__ q, const u16* __restrict__ kk, const u16* __restrict__ vv,
        const float* __restrict__ ntw, u16* __restrict__ txn) {
    int bid = blockIdx.x;
    int b = bid >> 11;
    int n = bid & 2047;
    __shared__ u16 sQ[4][24][32];
    __shared__ u16 sK[4][24][32];
    __shared__ u16 sV[4][24][32];
    __shared__ float sS[4][24][24];
    __shared__ float sO[24][128];
    int tid = threadIdx.x, lane = tid & 63, wid = tid >> 6;
    for (int idx = tid; idx < 3072; idx += 256) {
        int h = idx / 768;
        int rem = idx - h * 768;
        int t = rem >> 5;
        int d = rem & 31;
        size_t off = ((size_t)((b * 24 + t) * 2048 + n)) * 128 + h * 32 + d;
        sQ[h][t][d] = q[off];
        sK[h][t][d] = kk[off];
        sV[h][t][d] = vv[off];
    }
    __syncthreads();
    int h = wid;
    for (int i = lane; i < 576; i += 64) {
        int qi = i / 24, ki = i - qi * 24;
        float s = 0.f;
        #pragma unroll
        for (int c = 0; c < 32; ++c) s += b2f(sQ[h][qi][c]) * b2f(sK[h][ki][c]);
        sS[h][qi][ki] = s * 0.17677669529663687f;   // 32^-0.5
    }
    __syncthreads();
    if (lane < 24) {
        float m = -1e30f;
        #pragma unroll
        for (int c = 0; c < 24; ++c) m = fmaxf(m, sS[h][lane][c]);
        float e[24]; float sum = 0.f;
        #pragma unroll
        for (int c = 0; c < 24; ++c) { e[c] = __expf(sS[h][lane][c] - m); sum += e[c]; }
        float inv = 1.f / sum;
        #pragma unroll
        for (int c = 0; c < 24; ++c) sS[h][lane][c] = e[c] * inv;
    }
    __syncthreads();
    for (int i = lane; i < 768; i += 64) {
        int qi = i >> 5, d = i & 31;
        float acc = 0.f;
        #pragma unroll
        for (int c = 0; c < 24; ++c) acc += sS[h][qi][c] * b2f(sV[h][c][d]);
        sO[qi][h * 32 + d] = acc;
    }
    __syncthreads();
    for (int j = 0; j < 6; ++j) {
        int t = wid * 6 + j;
        float v0 = sO[t][lane], v1 = sO[t][lane + 64];
        float ss = v0 * v0 + v1 * v1;
        #pragma unroll
        for (int o = 32; o > 0; o >>= 1) ss += __shfl_xor(ss, o);
        float sc = rsqrtf(ss * (1.f / 128.f) + 1e-6f);
        size_t off = ((size_t)((b * 24 + t) * 2048 + n)) * 128;
        txn[off + lane]      = f2b(v0 * sc * ntw[lane]);
        txn[off + lane + 64] = f2b(v1 * sc * ntw[lane + 64]);
    }
}

// ---------------- K4: row-normalize adjacency -> bf16 ----------------
__global__ __launch_bounds__(256) void adj_norm(const float* __restrict__ adj, u16* __restrict__ abf) {
    int nrow = blockIdx.x;
    const float* r = adj + (size_t)nrow * 2048;
    int tid = threadIdx.x;
    float s = 0.f;
    for (int c = tid; c < 2048; c += 256) s += r[c];
    __shared__ float red[4];
    #pragma unroll
    for (int o = 32; o > 0; o >>= 1) s += __shfl_xor(s, o);
    if ((tid & 63) == 0) red[tid >> 6] = s;
    __syncthreads();
    float inv = 1.f / (red[0] + red[1] + red[2] + red[3]);
    u16* o = abf + (size_t)nrow * 2048;
    for (int c = tid; c < 2048; c += 256) o[c] = f2b(r[c] * inv);
}

// ---------------- K4t: transpose t_x_n per (b,t): [2048,128] -> [128,2048] ----------------
__global__ __launch_bounds__(256) void transpose_k(const u16* __restrict__ txn, u16* __restrict__ txT) {
    int bt = blockIdx.x >> 5;
    int n0 = (blockIdx.x & 31) * 64;
    int tid = threadIdx.x;
    int nn = tid & 63, dg = tid >> 6;     // 4 d-groups of 8
    for (int rep = 0; rep < 4; ++rep) {
        int d0 = rep * 32 + dg * 8;
        union { u32x4 v; u16 us[8]; } u;
        u.v = *(const u32x4*)(txn + ((size_t)(bt * 2048 + n0 + nn)) * 128 + d0);
        #pragma unroll
        for (int j = 0; j < 8; ++j)
            txT[((size_t)(bt * 128 + d0 + j)) * 2048 + n0 + nn] = u.us[j];
    }
}

// ---------------- K5: GCN mixed = a @ t_x  (per (b,t): [2048,2048]x[2048,128]) ----------------
// m97-structure: async global_load_lds (width=16) with pre-swizzled source.
__global__ __launch_bounds__(256) void gcn_gemm(
        const u16* __restrict__ abf, const u16* __restrict__ txT, u16* __restrict__ mixed) {
    int bt = blockIdx.x >> 4;
    int n0 = (blockIdx.x & 15) * 128;
    __shared__ u16 sA[128 * 64];
    __shared__ u16 sB[128 * 64];
    int tid = threadIdx.x, lane = tid & 63, ln15 = lane & 15, g16 = lane >> 4, wid = tid >> 6;
    int wm = (wid >> 1) * 64, wn = (wid & 1) * 64;
    f32x4 acc[4][4];
    zero_acc(acc);
    const u16* aRow = abf + (size_t)n0 * 2048;
    const u16* bRow = txT + (size_t)bt * 128 * 2048;
    for (int k0 = 0; k0 < 2048; k0 += 64) {
        __syncthreads();                 // previous compute's LDS reads done
        #pragma unroll
        for (int i = 0; i < 4; ++i) stage_async64(sA, aRow + k0, wid * 4 + i, lane);
        #pragma unroll
        for (int i = 0; i < 4; ++i) stage_async64(sB, bRow + k0, wid * 4 + i, lane);
        __syncthreads();                 // compiler drains vmcnt(0) before barrier
        #pragma unroll
        for (int ks = 0; ks < 2; ++ks)
            gemm_step64<64, 64>(sA, sB, wm, wn, ks * 64 + g16 * 16, acc, ln15);
    }
    u16* out = mixed + ((size_t)(bt * 2048 + n0)) * 128;
    #pragma unroll
    for (int i = 0; i < 4; ++i)
        #pragma unroll
        for (int j = 0; j < 4; ++j)
            #pragma unroll
            for (int r = 0; r < 4; ++r) {
                int row = wm + i * 16 + g16 * 4 + r;
                int col = wn + j * 16 + ln15;
                out[(size_t)row * 128 + col] = f2b(acc[i][j][r]);
            }
}

// ---------------- K6: gcn_fc1 + alpha-mix + gcn_mlp + residual + norm2 + router + top2 ----------------
__global__ __launch_bounds__(256) void fused_gcn_router(
        const u16* __restrict__ mixed, const u16* __restrict__ txn,
        const float* __restrict__ x,
        const u16* __restrict__ W1, const u16* __restrict__ W2,
        const float* __restrict__ bias2, const float* __restrict__ n2w,
        const float* __restrict__ gatew,
        float* __restrict__ outx, float* __restrict__ outlog,
        u16* __restrict__ x2n,
        int* __restrict__ lists, float* __restrict__ listw, int* __restrict__ cnts) {
    int tok0 = blockIdx.x * 128;
    __shared__ char LB[65536];
    __shared__ float sGate[1024];
    __shared__ float sN2[128];
    __shared__ float sBias[128];
    __shared__ float sLog[1024];
    __shared__ float sPart[256];
    __shared__ float sScale[128];
    __shared__ int sBCnt[8];
    __shared__ int sGBase[8];
    u16* sM = (u16*)LB;
    u16* sW = (u16*)(LB + 32768);
    float* sXn = (float*)LB;           // overlay, used after GEMM2
    int tid = threadIdx.x, lane = tid & 63, ln15 = lane & 15, g16 = lane >> 4, wid = tid >> 6;
    int wm = (wid >> 1) * 64, wn = (wid & 1) * 64;
    stage_bf16<128>(sM, mixed + (size_t)tok0 * 128, 128, 128, tid, 256);
    stage_bf16<128>(sW, W1, 128, 128, tid, 256);
    for (int i = tid; i < 1024; i += 256) sGate[i] = gatew[i];
    if (tid < 128) { sN2[tid] = n2w[tid]; sBias[tid] = bias2[tid]; }
    if (tid < 8) sBCnt[tid] = 0;
    __syncthreads();
    f32x4 acc[4][4];
    zero_acc(acc);
    #pragma unroll
    for (int ks = 0; ks < 4; ++ks)
        gemm_step64<128, 128>(sM, sW, wm, wn, ks * 64 + g16 * 16, acc, ln15);
    __syncthreads();
    // mixed & W1 dead: stage t_x over sM, W2 over sW
    stage_bf16<128>(sM, txn + (size_t)tok0 * 128, 128, 128, tid, 256);
    stage_bf16<128>(sW, W2, 128, 128, tid, 256);
    __syncthreads();
    // in-place alpha-mix: h = 0.05*t_x + 0.95*gcn_out (per-thread bijective cells)
    #pragma unroll
    for (int i = 0; i < 4; ++i)
        #pragma unroll
        for (int j = 0; j < 4; ++j)
            #pragma unroll
            for (int r = 0; r < 4; ++r) {
                int row = wm + i * 16 + g16 * 4 + r;
                int col = wn + j * 16 + ln15;
                float tv = b2f(lds_us<128>(sM, row, col));
                lds_store_us<128>(sM, row, col, f2b(0.05f * tv + 0.95f * acc[i][j][r]));
            }
    __syncthreads();
    zero_acc(acc);
    #pragma unroll
    for (int ks = 0; ks < 4; ++ks)
        gemm_step64<128, 128>(sM, sW, wm, wn, ks * 64 + g16 * 16, acc, ln15);
    // epilogue in regs: xv = x + ho + bias; write outx; keep xv in acc
    #pragma unroll
    for (int i = 0; i < 4; ++i)
        #pragma unroll
        for (int j = 0; j < 4; ++j)
            #pragma unroll
            for (int r = 0; r < 4; ++r) {
                int row = wm + i * 16 + g16 * 4 + r;
                int col = wn + j * 16 + ln15;
                float xv = x[(size_t)(tok0 + row) * 128 + col] + acc[i][j][r] + sBias[col];
                outx[(size_t)(tok0 + row) * 128 + col] = xv;
                acc[i][j][r] = xv;
            }
    // per-row sum of squares: reduce over 16 lanes (cols of this wave) -> sPart[row][wavehalf]
    #pragma unroll
    for (int i = 0; i < 4; ++i)
        #pragma unroll
        for (int r = 0; r < 4; ++r) {
            float s = 0.f;
            #pragma unroll
            for (int j = 0; j < 4; ++j) s += acc[i][j][r] * acc[i][j][r];
            s += __shfl_xor(s, 1); s += __shfl_xor(s, 2);
            s += __shfl_xor(s, 4); s += __shfl_xor(s, 8);
            if (ln15 == 0) sPart[(wm + i * 16 + g16 * 4 + r) * 2 + (wid & 1)] = s;
        }
    __syncthreads();   // also guarantees GEMM2's LDS reads are done before sXn overlay
    if (tid < 128)
        sScale[tid] = rsqrtf((sPart[tid * 2] + sPart[tid * 2 + 1]) * (1.f / 128.f) + 1e-6f);
    __syncthreads();
    // write f32 normalized tile into the 64KB overlay
    #pragma unroll
    for (int i = 0; i < 4; ++i)
        #pragma unroll
        for (int j = 0; j < 4; ++j)
            #pragma unroll
            for (int r = 0; r < 4; ++r) {
                int row = wm + i * 16 + g16 * 4 + r;
                int col = wn + j * 16 + ln15;
                sXn[row * 128 + col] = acc[i][j][r] * sScale[row] * sN2[col];
            }
    __syncthreads();
    {   // router logits (2 threads per row x 4 experts each); rotate c by r to dodge banks
        int r = tid >> 1, e0 = (tid & 1) * 4;
        float a0 = 0, a1 = 0, a2 = 0, a3 = 0;
        for (int cc = 0; cc < 128; ++cc) {
            int c = (cc + r) & 127;
            float v = sXn[r * 128 + c];
            a0 += v * sGate[(e0 + 0) * 128 + c];
            a1 += v * sGate[(e0 + 1) * 128 + c];
            a2 += v * sGate[(e0 + 2) * 128 + c];
            a3 += v * sGate[(e0 + 3) * 128 + c];
        }
        int rb = r * 8 + e0;
        sLog[rb + 0] = a0; sLog[rb + 1] = a1; sLog[rb + 2] = a2; sLog[rb + 3] = a3;
        size_t ob = (size_t)(tok0 + r) * 8 + e0;
        outlog[ob + 0] = a0; outlog[ob + 1] = a1; outlog[ob + 2] = a2; outlog[ob + 3] = a3;
    }
    // x2n store (bf16, vectorized) straight from the f32 overlay
    for (int cc = tid; cc < 2048; cc += 256) {
        int r = cc >> 4, c0 = (cc & 15) * 8;
        union { u32x4 v; u16 us[8]; } u;
        #pragma unroll
        for (int jj = 0; jj < 8; ++jj) u.us[jj] = f2b(sXn[r * 128 + c0 + jj]);
        *(u32x4*)(x2n + (size_t)(tok0 + r) * 128 + c0) = u.v;
    }
    __syncthreads();
    // top-2 with BLOCK-AGGREGATED list build (8 global atomics per block)
    // list payload = tok*2 + slot  (slot 0 = top-1 entry, 1 = top-2 entry)
    int e1 = 0, e2 = 0, le1 = 0, le2 = 0;
    float w1v = 0.f, w2v = 0.f;
    if (tid < 128) {
        int r = tid;
        float l[8];
        #pragma unroll
        for (int e = 0; e < 8; ++e) l[e] = sLog[r * 8 + e];
        float m = l[0];
        #pragma unroll
        for (int e = 1; e < 8; ++e) m = fmaxf(m, l[e]);
        float ex[8]; float s = 0.f;
        #pragma unroll
        for (int e = 0; e < 8; ++e) { ex[e] = __expf(l[e] - m); s += ex[e]; }
        float inv = 1.f / s;
        float b1v = ex[0]; e1 = 0;
        #pragma unroll
        for (int e = 1; e < 8; ++e) if (ex[e] > b1v) { b1v = ex[e]; e1 = e; }
        e2 = (e1 == 0) ? 1 : 0; float b2v = ex[e2];
        #pragma unroll
        for (int e = 0; e < 8; ++e) if (e != e1 && ex[e] > b2v) { b2v = ex[e]; e2 = e; }
        w1v = b1v * inv; w2v = b2v * inv;
        le1 = atomicAdd(&sBCnt[e1], 1);
        le2 = atomicAdd(&sBCnt[e2], 1);
    }
    __syncthreads();
    if (tid < 8) sGBase[tid] = atomicAdd(&cnts[tid], sBCnt[tid]);
    __syncthreads();
    if (tid < 128) {
        int tok = tok0 + tid;
        int p1 = sGBase[e1] + le1;
        lists[(size_t)e1 * TOK + p1] = tok * 2 + 0; listw[(size_t)e1 * TOK + p1] = w1v;
        int p2 = sGBase[e2] + le2;
        lists[(size_t)e2 * TOK + p2] = tok * 2 + 1; listw[(size_t)e2 * TOK + p2] = w2v;
    }
}

// ---------------- K7: sparse expert swiglu, IMAGE dbuf via global_load_lds ----------------
__global__ __launch_bounds__(256, 2) void moe_expert(
        const u16* __restrict__ x2n, const int* __restrict__ lists,
        const float* __restrict__ listw, const int* __restrict__ cnts,
        const u16* __restrict__ eimg, u16* __restrict__ slotOut) {
    int e = blockIdx.y;
    int base = blockIdx.x * 128;
    int cnt = cnts[e];
    if (base >= cnt) return;
    int valid = min(128, cnt - base);
    const int* lst = lists + (size_t)e * TOK + base;
    const float* lw = listw + (size_t)e * TOK + base;
    __shared__ u16 sBufA[13312];
    __shared__ u16 sBufB[13312];
    __shared__ u16 sH[5120];           // 128 rows x 80B
    __shared__ float sCoef[128];
    __shared__ int sTok[128];
    int tid = threadIdx.x, lane = tid & 63, ln15 = lane & 15, g16 = lane >> 4, wid = tid >> 6;
    const u16* imgbase = eimg + (size_t)(e * 8) * 13312;
    stage_img(sBufA, imgbase, wid, lane);              // chunk 0 async
    if (tid < 128) {
        int t = (tid < valid) ? lst[tid] : -1;
        sTok[tid] = t;
        sCoef[tid] = (tid < valid) ? lw[tid] : 0.f;
    }
    __syncthreads();                    // sTok visible; chunk0 resident
    // A-fragments gathered directly global->reg (each byte read once per block)
    bf16x8 av[2][4];
    {
        bf16x8 zz = {0, 0, 0, 0, 0, 0, 0, 0};
        int t0 = sTok[wid * 32 + ln15];
        int t1 = sTok[wid * 32 + 16 + ln15];
        const u16* r0 = x2n + (size_t)(t0 >> 1) * 128;
        const u16* r1 = x2n + (size_t)(t1 >> 1) * 128;
        #pragma unroll
        for (int ks = 0; ks < 4; ++ks) {
            av[0][ks] = (t0 >= 0) ? *(const bf16x8*)(r0 + ks * 32 + g16 * 8) : zz;
            av[1][ks] = (t1 >= 0) ? *(const bf16x8*)(r1 + ks * 32 + g16 * 8) : zz;
        }
    }
    f32x4 aout[2][8];
    f32x4 z = {0.f, 0.f, 0.f, 0.f};
    #pragma unroll
    for (int mf = 0; mf < 2; ++mf)
        #pragma unroll
        for (int nf = 0; nf < 8; ++nf) aout[mf][nf] = z;
    for (int ic = 0; ic < 8; ++ic) {
        u16* cur = (ic & 1) ? sBufB : sBufA;
        u16* alt = (ic & 1) ? sBufA : sBufB;
        if (ic + 1 < 8)
            stage_img(alt, imgbase + (size_t)(ic + 1) * 13312, wid, lane);
        swiglu_chunk(cur, sH, av, aout, wid, g16, ln15);
        __syncthreads();               // drains vmcnt -> alt resident; cur free
    }
    #pragma unroll
    for (int mf = 0; mf < 2; ++mf)
        #pragma unroll
        for (int nf = 0; nf < 8; ++nf)
            #pragma unroll
            for (int r = 0; r < 4; ++r) {
                int row = wid * 32 + mf * 16 + g16 * 4 + r;
                if (row < valid) {
                    int col = nf * 16 + ln15;
                    slotOut[(size_t)sTok[row] * 128 + col] = f2b(sCoef[row] * aout[mf][nf][r]);
                }
            }
}

// ---------------- K8: shared expert swiglu, IMAGE dbuf, + gate + combine ----------------
__global__ __launch_bounds__(256, 2) void moe_shared(
        const u16* __restrict__ x2n, const u16* __restrict__ simg,
        const float* __restrict__ sgw, const u16* __restrict__ slotOut,
        float* __restrict__ outx) {
    int tok0 = blockIdx.x * 128;
    __shared__ u16 sBufA[13312];
    __shared__ u16 sBufB[13312];
    __shared__ u16 sH[5120];
    __shared__ float sGv[128];
    int tid = threadIdx.x, lane = tid & 63, ln15 = lane & 15, g16 = lane >> 4, wid = tid >> 6;
    stage_img(sBufA, simg, wid, lane);                 // chunk 0 async
    // A-fragments direct global->reg (consecutive tokens: coalesced)
    bf16x8 av[2][4];
    {
        const u16* r0 = x2n + (size_t)(tok0 + wid * 32 + ln15) * 128;
        const u16* r1 = x2n + (size_t)(tok0 + wid * 32 + 16 + ln15) * 128;
        #pragma unroll
        for (int ks = 0; ks < 4; ++ks) {
            av[0][ks] = *(const bf16x8*)(r0 + ks * 32 + g16 * 8);
            av[1][ks] = *(const bf16x8*)(r1 + ks * 32 + g16 * 8);
        }
    }
    // sigmoid gate dot straight from global (sgw broadcast, x2n row per thread)
    if (tid < 128) {
        const u16* xr = x2n + (size_t)(tok0 + tid) * 128;
        float d = 0.f;
        #pragma unroll
        for (int c8 = 0; c8 < 16; ++c8) {
            bf16x8 v = *(const bf16x8*)(xr + c8 * 8);
            #pragma unroll
            for (int j = 0; j < 8; ++j) d += b2f((u16)v[j]) * sgw[c8 * 8 + j];
        }
        sGv[tid] = 1.f / (1.f + __expf(-d));
    }
    f32x4 aout[2][8];
    f32x4 z = {0.f, 0.f, 0.f, 0.f};
    #pragma unroll
    for (int mf = 0; mf < 2; ++mf)
        #pragma unroll
        for (int nf = 0; nf < 8; ++nf) aout[mf][nf] = z;
    __syncthreads();                    // chunk0 resident; sGv visible
    for (int ic = 0; ic < 16; ++ic) {
        u16* cur = (ic & 1) ? sBufB : sBufA;
        u16* alt = (ic & 1) ? sBufA : sBufB;
        if (ic + 1 < 16)
            stage_img(alt, simg + (size_t)(ic + 1) * 13312, wid, lane);
        swiglu_chunk(cur, sH, av, aout, wid, g16, ln15);
        __syncthreads();
    }
    #pragma unroll
    for (int mf = 0; mf < 2; ++mf)
        #pragma unroll
        for (int nf = 0; nf < 8; ++nf)
            #pragma unroll
            for (int r = 0; r < 4; ++r) {
                int row = wid * 32 + mf * 16 + g16 * 4 + r;
                int col = nf * 16 + ln15;
                size_t t = (size_t)(tok0 + row);
                float fc = b2f(slotOut[(t * 2 + 0) * 128 + col])
                         + b2f(slotOut[(t * 2 + 1) * 128 + col]);
                size_t idx = t * 128 + col;
                outx[idx] = outx[idx] + fc + sGv[row] * aout[mf][nf][r];
            }
}

// ---------------- host launcher ----------------
// workspace layout (bytes)
#define SZTD  ((size_t)TOK * 128 * 2)          // 50331648, one bf16 [Tok,128] buffer
#define OFF_XN   ((size_t)0)                   // x_n -> t_x_n
#define OFF_KN   (SZTD)                        // k_n -> mixed
#define OFF_Q    (SZTD * 2)                    // q -> t_xT -> x2n
#define OFF_KP   (SZTD * 3)                    // kp ; later slotOut bf16 [2*TOK][128] spans KP..KP+SZTD*2
#define OFF_VP   (SZTD * 4)                    // vp
#define OFF_ABF  (SZTD * 5)                    // a bf16 [2048,2048] = 8388608
#define OFF_LW   (OFF_ABF + 8388608)           // listw f32 [8*TOK]
#define OFF_LIST (OFF_LW + (size_t)8 * TOK * 4)
#define OFF_CNT  (OFF_LIST + (size_t)8 * TOK * 4)
#define OFF_ARENA (OFF_CNT + 128)              // bf16 arena: dense mats + chunk images

extern "C" void kernel_launch(void* const* d_in, const int* in_sizes, int n_in,
                              void* d_out, int out_size, void* d_ws, size_t ws_size,
                              hipStream_t stream) {
    (void)in_sizes; (void)n_in; (void)out_size; (void)ws_size;
    const float* x    = (const float*)d_in[0];
    const float* k    = (const float*)d_in[1];
    // d_in[2] (v) is unused by the reference
    const float* adj  = (const float*)d_in[3];
    const float* Wq   = (const float*)d_in[4];
    const float* bq   = (const float*)d_in[5];
    const float* Wk   = (const float*)d_in[6];
    const float* bk   = (const float*)d_in[7];
    const float* Wv   = (const float*)d_in[8];
    const float* bv   = (const float*)d_in[9];
    const float* ntw  = (const float*)d_in[10];
    const float* gfc1 = (const float*)d_in[11];
    const float* gmlp = (const float*)d_in[12];
    const float* gmlpb= (const float*)d_in[13];
    const float* n1w  = (const float*)d_in[14];
    const float* n2w  = (const float*)d_in[15];
    const float* gatew= (const float*)d_in[16];
    const float* ew1  = (const float*)d_in[17];
    const float* ew2  = (const float*)d_in[18];
    const float* ew3  = (const float*)d_in[19];
    const float* sw1  = (const float*)d_in[20];
    const float* sw2  = (const float*)d_in[21];
    const float* sw3  = (const float*)d_in[22];
    const float* sgw  = (const float*)d_in[23];

    char* ws = (char*)d_ws;
    u16*  xn   = (u16*)(ws + OFF_XN);
    u16*  kn   = (u16*)(ws + OFF_KN);
    u16*  qb   = (u16*)(ws + OFF_Q);
    u16*  kpb  = (u16*)(ws + OFF_KP);
    u16*  vpb  = (u16*)(ws + OFF_VP);
    u16*  slotOut = (u16*)(ws + OFF_KP);      // overlaps kp+vp (dead after attention)
    u16*  abf  = (u16*)(ws + OFF_ABF);
    float* lw  = (float*)(ws + OFF_LW);
    int*  lst  = (int*)(ws + OFF_LIST);
    int*  cnts = (int*)(ws + OFF_CNT);
    u16*  arena = (u16*)(ws + OFF_ARENA);
    u16*  bWq = arena;
    u16*  bWk = arena + 16384;
    u16*  bWv = arena + 32768;
    u16*  bG1 = arena + 49152;
    u16*  bG2 = arena + 65536;
    u16*  eimg = arena + 81920;               // 64 expert chunk images x 13312
    u16*  simg = arena + 933888;              // 16 shared chunk images x 13312
    float* outx   = (float*)d_out;
    float* outlog = outx + (size_t)TOK * 128;

    preconvert<<<600, 256, 0, stream>>>(Wq, Wk, Wv, gfc1, gmlp, ew1, ew2, ew3,
                                        sw1, sw2, sw3, arena, cnts);
    rmsnorm_pair<<<98304, 256, 0, stream>>>(x, k, n1w, xn, kn);
    proj128<<<1536, 256, 0, stream>>>(xn, bWq, bq, qb);
    proj128<<<1536, 256, 0, stream>>>(kn, bWk, bk, kpb);
    proj128<<<1536, 256, 0, stream>>>(kn, bWv, bv, vpb);
    attn_kernel<<<8192, 256, 0, stream>>>(qb, kpb, vpb, ntw, xn /* t_x_n */);
    adj_norm<<<2048, 256, 0, stream>>>(adj, abf);
    transpose_k<<<3072, 256, 0, stream>>>(xn, qb /* t_xT */);
    gcn_gemm<<<1536, 256, 0, stream>>>(abf, qb, kn /* mixed */);
    fused_gcn_router<<<1536, 256, 0, stream>>>(kn, xn, x, bG1, bG2, gmlpb, n2w, gatew,
                                               outx, outlog, qb /* x2n */, lst, lw, cnts);
    moe_expert<<<dim3(1536, 8), 256, 0, stream>>>(qb, lst, lw, cnts, eimg, slotOut);
    moe_shared<<<1536, 256, 0, stream>>>(qb, simg, sgw, slotOut, outx);
}

// Round 10
// 730.759 us; speedup vs baseline: 1.5246x; 1.0277x over previous
//
#include <hip/hip_runtime.h>

// ---------------- problem constants ----------------
#define BB 4
#define TT 24
#define NN 2048
#define DD 128
#define HH 4
#define HD 32
#define TOK 196608          // BB*TT*NN
#define EE 8
#define MINTER 256
#define INTER 512

typedef unsigned short u16;
typedef __attribute__((ext_vector_type(8))) short  bf16x8;
typedef __attribute__((ext_vector_type(4))) float  f32x4;
typedef __attribute__((ext_vector_type(4))) unsigned int u32x4;

#define MFMA(a,b,c) __builtin_amdgcn_mfma_f32_16x16x32_bf16((a),(b),(c),0,0,0)
#define AS(n) __attribute__((address_space(n)))

// ---------------- small helpers ----------------
static __device__ __forceinline__ u16 f2b(float f) {
    union { float f; unsigned u; } v; v.f = f;
    unsigned r = v.u + 0x7FFFu + ((v.u >> 16) & 1u);
    return (u16)(r >> 16);
}
static __device__ __forceinline__ u16 f2b_fast(float f) {   // truncate (1 op)
    union { float f; unsigned u; } v; v.f = f;
    return (u16)(v.u >> 16);
}
static __device__ __forceinline__ float b2f(u16 b) {
    union { unsigned u; float f; } v; v.u = ((unsigned)b) << 16;
    return v.f;
}
static __device__ __forceinline__ float silu_mul(float u, float v) {
    return u * __builtin_amdgcn_rcpf(1.f + __expf(-u)) * v;
}

// LDS tile helpers.  Tiles are [rows][C] bf16, row stride C*2 bytes, with a
// 16B-chunk XOR swizzle: chunk cc of row r lives at byte r*C*2 + ((cc*16) ^ ((r&mask)<<4)).
template<int C>
static __device__ __forceinline__ bf16x8 frag_ld(const u16* s, int row, int kbyte) {
    constexpr int mask = ((C/8) < 8 ? (C/8) : 8) - 1;
    int byte = row * (C * 2) + (kbyte ^ ((row & mask) << 4));
    return *(const bf16x8*)((const char*)s + byte);
}
template<int C>
static __device__ __forceinline__ u16 lds_us(const u16* s, int r, int c) {
    constexpr int mask = ((C/8) < 8 ? (C/8) : 8) - 1;
    int byte = r * (C * 2) + ((((c >> 3) << 4) ^ ((r & mask) << 4))) + ((c & 7) << 1);
    return *(const u16*)((const char*)s + byte);
}
template<int C>
static __device__ __forceinline__ void lds_store_us(u16* s, int r, int c, u16 v) {
    constexpr int mask = ((C/8) < 8 ? (C/8) : 8) - 1;
    int byte = r * (C * 2) + ((((c >> 3) << 4) ^ ((r & mask) << 4))) + ((c & 7) << 1);
    *(u16*)((char*)s + byte) = v;
}
// 80B-padded row stride (period-8 bank pattern, conflict-free for 16B reads)
static __device__ __forceinline__ bf16x8 frag_ld_p80(const u16* s, int row, int kbyte) {
    return *(const bf16x8*)((const char*)s + row * 80 + kbyte);
}
static __device__ __forceinline__ void sh_store_p80(u16* s, int r, int c, u16 v) {
    *(u16*)((char*)s + r * 80 + c * 2) = v;
}
// stage bf16 global -> swizzled LDS tile (reg path)
template<int C>
static __device__ __forceinline__ void stage_bf16(u16* s, const u16* g, int gstride,
                                                  int rows, int tid, int nthr) {
    constexpr int cpr = C / 8;
    constexpr int mask = (cpr < 8 ? cpr : 8) - 1;
    for (int i = tid; i < rows * cpr; i += nthr) {
        int r = i / cpr, cc = i - r * cpr;
        u32x4 v = *(const u32x4*)(g + (size_t)r * gstride + cc * 8);
        *(u32x4*)((char*)s + r * (C * 2) + ((cc * 16) ^ ((r & mask) << 4))) = v;
    }
}
// rmsnorm f32 rows -> swizzled bf16 LDS tile [128][128] (wave handles 32 rows,
// coalesced float2 per lane, full-wave shfl reduce — rmsnorm_pair's pattern)
static __device__ __forceinline__ void stage_rms(u16* sA, const float* __restrict__ in,
        const float* __restrict__ nw, int tid) {
    int wid = tid >> 6, lane = tid & 63;
    float2 wv = *(const float2*)(nw + lane * 2);
    for (int rr = 0; rr < 32; ++rr) {
        int r = wid * 32 + rr;
        float2 v = *(const float2*)(in + (size_t)r * 128 + lane * 2);
        float ss = v.x * v.x + v.y * v.y;
        #pragma unroll
        for (int o = 32; o > 0; o >>= 1) ss += __shfl_xor(ss, o);
        float sc = rsqrtf(ss * (1.f / 128.f) + 1e-6f);
        unsigned pack = ((unsigned)f2b(v.y * sc * wv.y) << 16) | (unsigned)f2b(v.x * sc * wv.x);
        int byte = r * 256 + (((lane >> 2) * 16) ^ ((r & 7) << 4)) + ((lane & 3) << 2);
        *(unsigned*)((char*)sA + byte) = pack;
    }
}
// async stage for a [128][64] bf16 tile from row-major global (stride 2048):
// LDS linear dest (wave base + lane*16), PRE-SWIZZLED global source chunk.
static __device__ __forceinline__ void stage_async64(u16* s, const u16* g, int wi, int lane) {
    int slot = wi * 64 + lane;            // 16B-chunk index in [0,1024)
    int r = slot >> 3, c = slot & 7;
    const u16* src = g + r * 2048 + ((c ^ (r & 7)) << 3);
    __builtin_amdgcn_global_load_lds((const AS(1) void*)src,
                                     (AS(3) void*)(s + wi * 512), 16, 0, 0);
}
// async stage of a pre-built 26624B weight-chunk image: linear copy.
// 26 slots of 1024B; wave w handles slots w, w+4, ...
static __device__ __forceinline__ void stage_img(u16* buf, const u16* img, int wid, int lane) {
    #pragma unroll
    for (int t = 0; t < 7; ++t) {
        int wi = wid + t * 4;
        if (wi < 26)
            __builtin_amdgcn_global_load_lds((const AS(1) void*)(img + wi * 512 + lane * 8),
                                             (AS(3) void*)(buf + wi * 512), 16, 0, 0);
    }
}
static __device__ __forceinline__ void zero_acc(f32x4 acc[4][4]) {
    f32x4 z = {0.f, 0.f, 0.f, 0.f};
    #pragma unroll
    for (int i = 0; i < 4; ++i)
        #pragma unroll
        for (int j = 0; j < 4; ++j) acc[i][j] = z;
}
// one K-step (32) of a 64x64 wave tile: 4 A frags x 4 B frags -> 16 MFMA
template<int CA, int CB>
static __device__ __forceinline__ void gemm_step64(const u16* sA, const u16* sB,
        int arow0, int brow0, int kbyte, f32x4 acc[4][4], int ln15) {
    bf16x8 a[4], b[4];
    #pragma unroll
    for (int i = 0; i < 4; ++i) a[i] = frag_ld<CA>(sA, arow0 + i * 16 + ln15, kbyte);
    #pragma unroll
    for (int j = 0; j < 4; ++j) b[j] = frag_ld<CB>(sB, brow0 + j * 16 + ln15, kbyte);
    #pragma unroll
    for (int i = 0; i < 4; ++i)
        #pragma unroll
        for (int j = 0; j < 4; ++j)
            acc[i][j] = MFMA(a[i], b[j], acc[i][j]);
}

// one swiglu inter-chunk (32 wide) on a staged image buf:
// W1c [32][128] swz @0, W3c swz @4096 (u16), W2c [128] 80B rows @8192 (u16)
static __device__ __forceinline__ void swiglu_chunk(const u16* buf, u16* sH,
        const bf16x8 av[2][4], f32x4 aout[2][8],
        int wid, int g16, int ln15) {
    const u16* W1c = buf;
    const u16* W3c = buf + 4096;
    const u16* W2c = buf + 8192;
    f32x4 z = {0.f, 0.f, 0.f, 0.f};
    f32x4 a1[2][2], a3[2][2];
    #pragma unroll
    for (int mf = 0; mf < 2; ++mf)
        #pragma unroll
        for (int nf = 0; nf < 2; ++nf) { a1[mf][nf] = z; a3[mf][nf] = z; }
    __builtin_amdgcn_s_setprio(1);
    #pragma unroll
    for (int ks = 0; ks < 4; ++ks) {
        int kb = ks * 64 + g16 * 16;
        #pragma unroll
        for (int nf = 0; nf < 2; ++nf) {
            bf16x8 b1 = frag_ld<128>(W1c, nf * 16 + ln15, kb);
            bf16x8 b3 = frag_ld<128>(W3c, nf * 16 + ln15, kb);
            a1[0][nf] = MFMA(av[0][ks], b1, a1[0][nf]);
            a1[1][nf] = MFMA(av[1][ks], b1, a1[1][nf]);
            a3[0][nf] = MFMA(av[0][ks], b3, a3[0][nf]);
            a3[1][nf] = MFMA(av[1][ks], b3, a3[1][nf]);
        }
    }
    __builtin_amdgcn_s_setprio(0);
    #pragma unroll
    for (int mf = 0; mf < 2; ++mf)
        #pragma unroll
        for (int nf = 0; nf < 2; ++nf)
            #pragma unroll
            for (int r = 0; r < 4; ++r) {
                int row = wid * 32 + mf * 16 + g16 * 4 + r;
                int col = nf * 16 + ln15;
                sh_store_p80(sH, row, col, f2b_fast(silu_mul(a1[mf][nf][r], a3[mf][nf][r])));
            }
    // sH rows are wave-private: wave w writes & reads only rows w*32..w*32+31
    asm volatile("s_waitcnt lgkmcnt(0)" ::: "memory");
    __builtin_amdgcn_sched_barrier(0);
    {
        int kb = g16 * 16;
        bf16x8 ah0 = frag_ld_p80(sH, wid * 32 + ln15, kb);
        bf16x8 ah1 = frag_ld_p80(sH, wid * 32 + 16 + ln15, kb);
        __builtin_amdgcn_s_setprio(1);
        #pragma unroll
        for (int nf = 0; nf < 8; ++nf) {
            bf16x8 bw = frag_ld_p80(W2c, nf * 16 + ln15, kb);
            aout[0][nf] = MFMA(ah0, bw, aout[0][nf]);
            aout[1][nf] = MFMA(ah1, bw, aout[1][nf]);
        }
        __builtin_amdgcn_s_setprio(0);
    }
}

// ---------------- K0: preconvert weights -> bf16 arena (dense mats + MoE chunk IMAGES) ----
// arena u16 offsets: Wq 0, Wk 16384, Wv 32768, g1 49152, g2 65536,
// expert images @81920 (64 images x 13312), shared images @933888 (16 x 13312).
// image: [W1c 32x128 swz | W3c 32x128 swz | W2c 128 rows x 80B padded]
__global__ __launch_bounds__(256) void preconvert(
        const float* __restrict__ Wq, const float* __restrict__ Wk,
        const float* __restrict__ Wv, const float* __restrict__ g1,
        const float* __restrict__ g2,
        const float* __restrict__ e1, const float* __restrict__ e2,
        const float* __restrict__ e3,
        const float* __restrict__ s1, const float* __restrict__ s2,
        const float* __restrict__ s3,
        u16* __restrict__ arena, int* __restrict__ cnts) {
    int idx = blockIdx.x * 256 + threadIdx.x;
    if (blockIdx.x == 0 && threadIdx.x < 8) cnts[threadIdx.x] = 0;
    if (idx < 20480) {      // dense mats, 4-elem granularity
        int s = idx >> 12, rel = idx & 4095;
        const float* src = (s == 0) ? Wq : (s == 1) ? Wk : (s == 2) ? Wv : (s == 3) ? g1 : g2;
        const float4 v = *(const float4*)(src + (size_t)rel * 4);
        union { unsigned long long q; u16 us[4]; } o;
        o.us[0] = f2b(v.x); o.us[1] = f2b(v.y); o.us[2] = f2b(v.z); o.us[3] = f2b(v.w);
        *(unsigned long long*)(arena + (size_t)idx * 4) = o.q;
        return;
    }
    int p = idx - 20480;                 // image 16B-chunk index
    if (p >= 133120) return;             // 64*1664 + 16*1664
    const float *w1s, *w3s, *w2s_; int w2stride, ic;
    u16* img;
    if (p < 106496) {                    // expert images
        int imgIdx = p / 1664;
        p -= imgIdx * 1664;
        int e = imgIdx >> 3; ic = imgIdx & 7;
        w1s = e1 + (size_t)e * 32768;    // [256][128]
        w3s = e3 + (size_t)e * 32768;
        w2s_ = e2 + (size_t)e * 32768;   // [128][256]
        w2stride = 256;
        img = arena + 81920 + (size_t)imgIdx * 13312;
    } else {
        int q = p - 106496;
        int imgIdx = q / 1664; ic = imgIdx;
        p = q - imgIdx * 1664;
        w1s = s1; w3s = s3; w2s_ = s2; w2stride = 512;
        img = arena + 933888 + (size_t)imgIdx * 13312;
    }
    const float* src;
    if (p < 1024) {                      // W1/W3 swizzled regions
        const float* wsrc = (p < 512) ? w1s : w3s;
        int pp = p & 511;
        int r = pp >> 4, chq = pp & 15;
        int cc = chq ^ (r & 7);
        src = wsrc + (size_t)(ic * 32 + r) * 128 + cc * 8;
    } else {                             // W2 padded region
        int q = p - 1024;
        int r = q / 5, cc = q - r * 5;
        if (cc == 4) {                   // pad chunk
            u32x4 zv = {0, 0, 0, 0};
            *(u32x4*)(img + (size_t)p * 8) = zv;
            return;
        }
        src = w2s_ + (size_t)r * w2stride + ic * 32 + cc * 8;
    }
    union { u32x4 v; u16 us[8]; } o;
    #pragma unroll
    for (int j = 0; j < 8; ++j) o.us[j] = f2b(src[j]);
    *(u32x4*)(img + (size_t)p * 8) = o.v;
}

// ---------------- K2a: Q projection with fused rmsnorm (raw f32 x input) ----------------
__global__ __launch_bounds__(256) void proj_rms(
        const float* __restrict__ xin, const u16* __restrict__ W,
        const float* __restrict__ bias, const float* __restrict__ nw,
        u16* __restrict__ out) {
    int tok0 = blockIdx.x * 128;
    __shared__ u16 sA[128 * 128];
    __shared__ u16 sW[128 * 128];
    int tid = threadIdx.x, lane = tid & 63, ln15 = lane & 15, g16 = lane >> 4, wid = tid >> 6;
    int wm = (wid >> 1) * 64, wn = (wid & 1) * 64;
    stage_rms(sA, xin + (size_t)tok0 * 128, nw, tid);
    stage_bf16<128>(sW, W, 128, 128, tid, 256);
    __syncthreads();
    f32x4 acc[4][4];
    zero_acc(acc);
    #pragma unroll
    for (int ks = 0; ks < 4; ++ks)
        gemm_step64<128, 128>(sA, sW, wm, wn, ks * 64 + g16 * 16, acc, ln15);
    #pragma unroll
    for (int j = 0; j < 4; ++j) {
        int col = wn + j * 16 + ln15;
        float bv = bias[col];
        #pragma unroll
        for (int i = 0; i < 4; ++i)
            #pragma unroll
            for (int r = 0; r < 4; ++r) {
                int row = wm + i * 16 + g16 * 4 + r;
                out[(size_t)(tok0 + row) * 128 + col] = f2b(acc[i][j][r] + bv);
            }
    }
}

// ---------------- K2b: K and V projections with fused rmsnorm (k staged once) ----------------
__global__ __launch_bounds__(256) void projkv_rms(
        const float* __restrict__ kin, const u16* __restrict__ Wk,
        const float* __restrict__ bk, const u16* __restrict__ Wv,
        const float* __restrict__ bv, const float* __restrict__ nw,
        u16* __restrict__ kout, u16* __restrict__ vout) {
    int tok0 = blockIdx.x * 128;
    __shared__ u16 sA[128 * 128];
    __shared__ u16 sW[128 * 128];
    int tid = threadIdx.x, lane = tid & 63, ln15 = lane & 15, g16 = lane >> 4, wid = tid >> 6;
    int wm = (wid >> 1) * 64, wn = (wid & 1) * 64;
    stage_rms(sA, kin + (size_t)tok0 * 128, nw, tid);
    stage_bf16<128>(sW, Wk, 128, 128, tid, 256);
    __syncthreads();
    f32x4 acc[4][4];
    zero_acc(acc);
    #pragma unroll
    for (int ks = 0; ks < 4; ++ks)
        gemm_step64<128, 128>(sA, sW, wm, wn, ks * 64 + g16 * 16, acc, ln15);
    #pragma unroll
    for (int j = 0; j < 4; ++j) {
        int col = wn + j * 16 + ln15;
        float bvv = bk[col];
        #pragma unroll
        for (int i = 0; i < 4; ++i)
            #pragma unroll
            for (int r = 0; r < 4; ++r) {
                int row = wm + i * 16 + g16 * 4 + r;
                kout[(size_t)(tok0 + row) * 128 + col] = f2b(acc[i][j][r] + bvv);
            }
    }
    __syncthreads();                     // all GEMM1 LDS reads done
    stage_bf16<128>(sW, Wv, 128, 128, tid, 256);
    __syncthreads();
    zero_acc(acc);
    #pragma unroll
    for (int ks = 0; ks < 4; ++ks)
        gemm_step64<128, 128>(sA, sW, wm, wn, ks * 64 + g16 * 16, acc, ln15);
    #pragma unroll
    for (int j = 0; j < 4; ++j) {
        int col = wn + j * 16 + ln15;
        float bvv = bv[col];
        #pragma unroll
        for (int i = 0; i < 4; ++i)
            #pragma unroll
            for (int r = 0; r < 4; ++r) {
                int row = wm + i * 16 + g16 * 4 + r;
                vout[(size_t)(tok0 + row) * 128 + col] = f2b(acc[i][j][r] + bvv);
            }
    }
}

// ---------------- K3: attention over T per (b,n), all 4 heads, fused rmsnorm ----------------
__global__ __launch_bounds__(256) void attn_kernel(
        const u16* __restrict__ q, const u16* __restrict__ kk, const u16* __restrict__ vv,
        const float* __restrict__ ntw, u16* __restrict__ txn) {
    int bid = blockIdx.x;
    int b = bid >> 11;
    int n = bid & 2047;
    __shared__ u16 sQ[4][24][32];
    __shared__ u16 sK[4][24][32];
    __shared__ u16 sV[4][24][32];
    __shared__ float sS[4][24][24];
    __shared__ float sO[24][128];
    int tid = threadIdx.x, lane = tid & 63, wid = tid >> 6;
    for (int idx = tid; idx < 3072; idx += 256) {
        int h = idx / 768;
        int rem = idx - h * 768;
        int t = rem >> 5;
        int d = rem & 31;
        size_t off = ((size_t)((b * 24 + t) * 2048 + n)) * 128 + h * 32 + d;
        sQ[h][t][d] = q[off];
        sK[h][t][d] = kk[off];
        sV[h][t][d] = vv[off];
    }
    __syncthreads();
    int h = wid;
    for (int i = lane; i < 576; i += 64) {
        int qi = i / 24, ki = i - qi * 24;
        float s = 0.f;
        #pragma unroll
        for (int c = 0; c < 32; ++c) s += b2f(sQ[h][qi][c]) * b2f(sK[h][ki][c]);
        sS[h][qi][ki] = s * 0.17677669529663687f;   // 32^-0.5
    }
    __syncthreads();
    if (lane < 24) {
        float m = -1e30f;
        #pragma unroll
        for (int c = 0; c < 24; ++c) m = fmaxf(m, sS[h][lane][c]);
        float e[24]; float sum = 0.f;
        #pragma unroll
        for (int c = 0; c < 24; ++c) { e[c] = __expf(sS[h][lane][c] - m); sum += e[c]; }
        float inv = 1.f / sum;
        #pragma unroll
        for (int c = 0; c < 24; ++c) sS[h][lane][c] = e[c] * inv;
    }
    __syncthreads();
    for (int i = lane; i < 768; i += 64) {
        int qi = i >> 5, d = i & 31;
        float acc = 0.f;
        #pragma unroll
        for (int c = 0; c < 24; ++c) acc += sS[h][qi][c] * b2f(sV[h][c][d]);
        sO[qi][h * 32 + d] = acc;
    }
    __syncthreads();
    for (int j = 0; j < 6; ++j) {
        int t = wid * 6 + j;
        float v0 = sO[t][lane], v1 = sO[t][lane + 64];
        float ss = v0 * v0 + v1 * v1;
        #pragma unroll
        for (int o = 32; o > 0; o >>= 1) ss += __shfl_xor(ss, o);
        float sc = rsqrtf(ss * (1.f / 128.f) + 1e-6f);
        size_t off = ((size_t)((b * 24 + t) * 2048 + n)) * 128;
        txn[off + lane]      = f2b(v0 * sc * ntw[lane]);
        txn[off + lane + 64] = f2b(v1 * sc * ntw[lane + 64]);
    }
}

// ---------------- K4: row-normalize adjacency -> bf16 ----------------
__global__ __launch_bounds__(256) void adj_norm(const float* __restrict__ adj, u16* __restrict__ abf) {
    int nrow = blockIdx.x;
    const float* r = adj + (size_t)nrow * 2048;
    int tid = threadIdx.x;
    float s = 0.f;
    for (int c = tid; c < 2048; c += 256) s += r[c];
    __shared__ float red[4];
    #pragma unroll
    for (int o = 32; o > 0; o >>= 1) s += __shfl_xor(s, o);
    if ((tid & 63) == 0) red[tid >> 6] = s;
    __syncthreads();
    float inv = 1.f / (red[0] + red[1] + red[2] + red[3]);
    u16* o = abf + (size_t)nrow * 2048;
    for (int c = tid; c < 2048; c += 256) o[c] = f2b(r[c] * inv);
}

// ---------------- K4t: transpose t_x_n per (b,t): [2048,128] -> [128,2048] ----------------
__global__ __launch_bounds__(256) void transpose_k(const u16* __restrict__ txn, u16* __restrict__ txT) {
    int bt = blockIdx.x >> 5;
    int n0 = (blockIdx.x & 31) * 64;
    int tid = threadIdx.x;
    int nn = tid & 63, dg = tid >> 6;     // 4 d-groups of 8
    for (int rep = 0; rep < 4; ++rep) {
        int d0 = rep * 32 + dg * 8;
        union { u32x4 v; u16 us[8]; } u;
        u.v = *(const u32x4*)(txn + ((size_t)(bt * 2048 + n0 + nn)) * 128 + d0);
        #pragma unroll
        for (int j = 0; j < 8; ++j)
            txT[((size_t)(bt * 128 + d0 + j)) * 2048 + n0 + nn] = u.us[j];
    }
}

// ---------------- K5: GCN mixed = a @ t_x  (per (b,t): [2048,2048]x[2048,128]) ----------------
// m97-structure: async global_load_lds (width=16) with pre-swizzled source.
__global__ __launch_bounds__(256) void gcn_gemm(
        const u16* __restrict__ abf, const u16* __restrict__ txT, u16* __restrict__ mixed) {
    int bt = blockIdx.x >> 4;
    int n0 = (blockIdx.x & 15) * 128;
    __shared__ u16 sA[128 * 64];
    __shared__ u16 sB[128 * 64];
    int tid = threadIdx.x, lane = tid & 63, ln15 = lane & 15, g16 = lane >> 4, wid = tid >> 6;
    int wm = (wid >> 1) * 64, wn = (wid & 1) * 64;
    f32x4 acc[4][4];
    zero_acc(acc);
    const u16* aRow = abf + (size_t)n0 * 2048;
    const u16* bRow = txT + (size_t)bt * 128 * 2048;
    for (int k0 = 0; k0 < 2048; k0 += 64) {
        __syncthreads();                 // previous compute's LDS reads done
        #pragma unroll
        for (int i = 0; i < 4; ++i) stage_async64(sA, aRow + k0, wid * 4 + i, lane);
        #pragma unroll
        for (int i = 0; i < 4; ++i) stage_async64(sB, bRow + k0, wid * 4 + i, lane);
        __syncthreads();                 // compiler drains vmcnt(0) before barrier
        #pragma unroll
        for (int ks = 0; ks < 2; ++ks)
            gemm_step64<64, 64>(sA, sB, wm, wn, ks * 64 + g16 * 16, acc, ln15);
    }
    u16* out = mixed + ((size_t)(bt * 2048 + n0)) * 128;
    #pragma unroll
    for (int i = 0; i < 4; ++i)
        #pragma unroll
        for (int j = 0; j < 4; ++j)
            #pragma unroll
            for (int r = 0; r < 4; ++r) {
                int row = wm + i * 16 + g16 * 4 + r;
                int col = wn + j * 16 + ln15;
                out[(size_t)row * 128 + col] = f2b(acc[i][j][r]);
            }
}

// ---------------- K6: gcn_fc1 + alpha-mix + gcn_mlp + residual + norm2 + router + top2 ----------------
__global__ __launch_bounds__(256) void fused_gcn_router(
        const u16* __restrict__ mixed, const u16* __restrict__ txn,
        const float* __restrict__ x,
        const u16* __restrict__ W1, const u16* __restrict__ W2,
        const float* __restrict__ bias2, const float* __restrict__ n2w,
        const float* __restrict__ gatew,
        float* __restrict__ outx, float* __restrict__ outlog,
        u16* __restrict__ x2n,
        int* __restrict__ lists, float* __restrict__ listw, int* __restrict__ cnts) {
    int tok0 = blockIdx.x * 128;
    __shared__ char LB[65536];
    __shared__ float sGate[1024];
    __shared__ float sN2[128];
    __shared__ float sBias[128];
    __shared__ float sLog[1024];
    __shared__ float sPart[256];
    __shared__ float sScale[128];
    __shared__ int sBCnt[8];
    __shared__ int sGBase[8];
    u16* sM = (u16*)LB;
    u16* sW = (u16*)(LB + 32768);
    float* sXn = (float*)LB;           // overlay, used after GEMM2
    int tid = threadIdx.x, lane = tid & 63, ln15 = lane & 15, g16 = lane >> 4, wid = tid >> 6;
    int wm = (wid >> 1) * 64, wn = (wid & 1) * 64;
    stage_bf16<128>(sM, mixed + (size_t)tok0 * 128, 128, 128, tid, 256);
    stage_bf16<128>(sW, W1, 128, 128, tid, 256);
    for (int i = tid; i < 1024; i += 256) sGate[i] = gatew[i];
    if (tid < 128) { sN2[tid] = n2w[tid]; sBias[tid] = bias2[tid]; }
    if (tid < 8) sBCnt[tid] = 0;
    __syncthreads();
    f32x4 acc[4][4];
    zero_acc(acc);
    #pragma unroll
    for (int ks = 0; ks < 4; ++ks)
        gemm_step64<128, 128>(sM, sW, wm, wn, ks * 64 + g16 * 16, acc, ln15);
    __syncthreads();
    // mixed & W1 dead: stage t_x over sM, W2 over sW
    stage_bf16<128>(sM, txn + (size_t)tok0 * 128, 128, 128, tid, 256);
    stage_bf16<128>(sW, W2, 128, 128, tid, 256);
    __syncthreads();
    // in-place alpha-mix: h = 0.05*t_x + 0.95*gcn_out (per-thread bijective cells)
    #pragma unroll
    for (int i = 0; i < 4; ++i)
        #pragma unroll
        for (int j = 0; j < 4; ++j)
            #pragma unroll
            for (int r = 0; r < 4; ++r) {
                int row = wm + i * 16 + g16 * 4 + r;
                int col = wn + j * 16 + ln15;
                float tv = b2f(lds_us<128>(sM, row, col));
                lds_store_us<128>(sM, row, col, f2b(0.05f * tv + 0.95f * acc[i][j][r]));
            }
    __syncthreads();
    zero_acc(acc);
    #pragma unroll
    for (int ks = 0; ks < 4; ++ks)
        gemm_step64<128, 128>(sM, sW, wm, wn, ks * 64 + g16 * 16, acc, ln15);
    // epilogue in regs: xv = x + ho + bias; write outx; keep xv in acc
    #pragma unroll
    for (int i = 0; i < 4; ++i)
        #pragma unroll
        for (int j = 0; j < 4; ++j)
            #pragma unroll
            for (int r = 0; r < 4; ++r) {
                int row = wm + i * 16 + g16 * 4 + r;
                int col = wn + j * 16 + ln15;
                float xv = x[(size_t)(tok0 + row) * 128 + col] + acc[i][j][r] + sBias[col];
                outx[(size_t)(tok0 + row) * 128 + col] = xv;
                acc[i][j][r] = xv;
            }
    // per-row sum of squares: reduce over 16 lanes (cols of this wave) -> sPart[row][wavehalf]
    #pragma unroll
    for (int i = 0; i < 4; ++i)
        #pragma unroll
        for (int r = 0; r < 4; ++r) {
            float s = 0.f;
            #pragma unroll
            for (int j = 0; j < 4; ++j) s += acc[i][j][r] * acc[i][j][r];
            s += __shfl_xor(s, 1); s += __shfl_xor(s, 2);
            s += __shfl_xor(s, 4); s += __shfl_xor(s, 8);
            if (ln15 == 0) sPart[(wm + i * 16 + g16 * 4 + r) * 2 + (wid & 1)] = s;
        }
    __syncthreads();   // also guarantees GEMM2's LDS reads are done before sXn overlay
    if (tid < 128)
        sScale[tid] = rsqrtf((sPart[tid * 2] + sPart[tid * 2 + 1]) * (1.f / 128.f) + 1e-6f);
    __syncthreads();
    // write f32 normalized tile into the 64KB overlay
    #pragma unroll
    for (int i = 0; i < 4; ++i)
        #pragma unroll
        for (int j = 0; j < 4; ++j)
            #pragma unroll
            for (int r = 0; r < 4; ++r) {
                int row = wm + i * 16 + g16 * 4 + r;
                int col = wn + j * 16 + ln15;
                sXn[row * 128 + col] = acc[i][j][r] * sScale[row] * sN2[col];
            }
    __syncthreads();
    {   // router logits (2 threads per row x 4 experts each); rotate c by r to dodge banks
        int r = tid >> 1, e0 = (tid & 1) * 4;
        float a0 = 0, a1 = 0, a2 = 0, a3 = 0;
        for (int cc = 0; cc < 128; ++cc) {
            int c = (cc + r) & 127;
            float v = sXn[r * 128 + c];
            a0 += v * sGate[(e0 + 0) * 128 + c];
            a1 += v * sGate[(e0 + 1) * 128 + c];
            a2 += v * sGate[(e0 + 2) * 128 + c];
            a3 += v * sGate[(e0 + 3) * 128 + c];
        }
        int rb = r * 8 + e0;
        sLog[rb + 0] = a0; sLog[rb + 1] = a1; sLog[rb + 2] = a2; sLog[rb + 3] = a3;
        size_t ob = (size_t)(tok0 + r) * 8 + e0;
        outlog[ob + 0] = a0; outlog[ob + 1] = a1; outlog[ob + 2] = a2; outlog[ob + 3] = a3;
    }
    // x2n store (bf16, vectorized) straight from the f32 overlay
    for (int cc = tid; cc < 2048; cc += 256) {
        int r = cc >> 4, c0 = (cc & 15) * 8;
        union { u32x4 v; u16 us[8]; } u;
        #pragma unroll
        for (int jj = 0; jj < 8; ++jj) u.us[jj] = f2b(sXn[r * 128 + c0 + jj]);
        *(u32x4*)(x2n + (size_t)(tok0 + r) * 128 + c0) = u.v;
    }
    __syncthreads();
    // top-2 with BLOCK-AGGREGATED list build (8 global atomics per block)
    // list payload = tok*2 + slot  (slot 0 = top-1 entry, 1 = top-2 entry)
    int e1 = 0, e2 = 0, le1 = 0, le2 = 0;
    float w1v = 0.f, w2v = 0.f;
    if (tid < 128) {
        int r = tid;
        float l[8];
        #pragma unroll
        for (int e = 0; e < 8; ++e) l[e] = sLog[r * 8 + e];
        float m = l[0];
        #pragma unroll
        for (int e = 1; e < 8; ++e) m = fmaxf(m, l[e]);
        float ex[8]; float s = 0.f;
        #pragma unroll
        for (int e = 0; e < 8; ++e) { ex[e] = __expf(l[e] - m); s += ex[e]; }
        float inv = 1.f / s;
        float b1v = ex[0]; e1 = 0;
        #pragma unroll
        for (int e = 1; e < 8; ++e) if (ex[e] > b1v) { b1v = ex[e]; e1 = e; }
        e2 = (e1 == 0) ? 1 : 0; float b2v = ex[e2];
        #pragma unroll
        for (int e = 0; e < 8; ++e) if (e != e1 && ex[e] > b2v) { b2v = ex[e]; e2 = e; }
        w1v = b1v * inv; w2v = b2v * inv;
        le1 = atomicAdd(&sBCnt[e1], 1);
        le2 = atomicAdd(&sBCnt[e2], 1);
    }
    __syncthreads();
    if (tid < 8) sGBase[tid] = atomicAdd(&cnts[tid], sBCnt[tid]);
    __syncthreads();
    if (tid < 128) {
        int tok = tok0 + tid;
        int p1 = sGBase[e1] + le1;
        lists[(size_t)e1 * TOK + p1] = tok * 2 + 0; listw[(size_t)e1 * TOK + p1] = w1v;
        int p2 = sGBase[e2] + le2;
        lists[(size_t)e2 * TOK + p2] = tok * 2 + 1; listw[(size_t)e2 * TOK + p2] = w2v;
    }
}

// ---------------- K7: sparse expert swiglu, IMAGE dbuf via global_load_lds ----------------
__global__ __launch_bounds__(256, 2) void moe_expert(
        const u16* __restrict__ x2n, const int* __restrict__ lists,
        const float* __restrict__ listw, const int* __restrict__ cnts,
        const u16* __restrict__ eimg, u16* __restrict__ slotOut) {
    int e = blockIdx.y;
    int base = blockIdx.x * 128;
    int cnt = cnts[e];
    if (base >= cnt) return;
    int valid = min(128, cnt - base);
    const int* lst = lists + (size_t)e * TOK + base;
    const float* lw = listw + (size_t)e * TOK + base;
    __shared__ u16 sBufA[13312];
    __shared__ u16 sBufB[13312];
    __shared__ u16 sH[5120];           // 128 rows x 80B
    __shared__ float sCoef[128];
    __shared__ int sTok[128];
    int tid = threadIdx.x, lane = tid & 63, ln15 = lane & 15, g16 = lane >> 4, wid = tid >> 6;
    const u16* imgbase = eimg + (size_t)(e * 8) * 13312;
    stage_img(sBufA, imgbase, wid, lane);              // chunk 0 async
    if (tid < 128) {
        int t = (tid < valid) ? lst[tid] : -1;
        sTok[tid] = t;
        sCoef[tid] = (tid < valid) ? lw[tid] : 0.f;
    }
    __syncthreads();                    // sTok visible; chunk0 resident
    // A-fragments gathered directly global->reg (each byte read once per block)
    bf16x8 av[2][4];
    {
        bf16x8 zz = {0, 0, 0, 0, 0, 0, 0, 0};
        int t0 = sTok[wid * 32 + ln15];
        int t1 = sTok[wid * 32 + 16 + ln15];
        const u16* r0 = x2n + (size_t)(t0 >> 1) * 128;
        const u16* r1 = x2n + (size_t)(t1 >> 1) * 128;
        #pragma unroll
        for (int ks = 0; ks < 4; ++ks) {
            av[0][ks] = (t0 >= 0) ? *(const bf16x8*)(r0 + ks * 32 + g16 * 8) : zz;
            av[1][ks] = (t1 >= 0) ? *(const bf16x8*)(r1 + ks * 32 + g16 * 8) : zz;
        }
    }
    f32x4 aout[2][8];
    f32x4 z = {0.f, 0.f, 0.f, 0.f};
    #pragma unroll
    for (int mf = 0; mf < 2; ++mf)
        #pragma unroll
        for (int nf = 0; nf < 8; ++nf) aout[mf][nf] = z;
    for (int ic = 0; ic < 8; ++ic) {
        u16* cur = (ic & 1) ? sBufB : sBufA;
        u16* alt = (ic & 1) ? sBufA : sBufB;
        if (ic + 1 < 8)
            stage_img(alt, imgbase + (size_t)(ic + 1) * 13312, wid, lane);
        swiglu_chunk(cur, sH, av, aout, wid, g16, ln15);
        __syncthreads();               // drains vmcnt -> alt resident; cur free
    }
    #pragma unroll
    for (int mf = 0; mf < 2; ++mf)
        #pragma unroll
        for (int nf = 0; nf < 8; ++nf)
            #pragma unroll
            for (int r = 0; r < 4; ++r) {
                int row = wid * 32 + mf * 16 + g16 * 4 + r;
                if (row < valid) {
                    int col = nf * 16 + ln15;
                    slotOut[(size_t)sTok[row] * 128 + col] = f2b_fast(sCoef[row] * aout[mf][nf][r]);
                }
            }
}

// ---------------- K8: shared expert swiglu, IMAGE dbuf, + gate + combine ----------------
__global__ __launch_bounds__(256, 2) void moe_shared(
        const u16* __restrict__ x2n, const u16* __restrict__ simg,
        const float* __restrict__ sgw, const u16* __restrict__ slotOut,
        float* __restrict__ outx) {
    int tok0 = blockIdx.x * 128;
    __shared__ u16 sBufA[13312];
    __shared__ u16 sBufB[13312];
    __shared__ u16 sH[5120];
    __shared__ float sGv[128];
    int tid = threadIdx.x, lane = tid & 63, ln15 = lane & 15, g16 = lane >> 4, wid = tid >> 6;
    stage_img(sBufA, simg, wid, lane);                 // chunk 0 async
    // A-fragments direct global->reg (consecutive tokens: coalesced)
    bf16x8 av[2][4];
    {
        const u16* r0 = x2n + (size_t)(tok0 + wid * 32 + ln15) * 128;
        const u16* r1 = x2n + (size_t)(tok0 + wid * 32 + 16 + ln15) * 128;
        #pragma unroll
        for (int ks = 0; ks < 4; ++ks) {
            av[0][ks] = *(const bf16x8*)(r0 + ks * 32 + g16 * 8);
            av[1][ks] = *(const bf16x8*)(r1 + ks * 32 + g16 * 8);
        }
    }
    // sigmoid gate dot straight from global (sgw broadcast, x2n row per thread)
    if (tid < 128) {
        const u16* xr = x2n + (size_t)(tok0 + tid) * 128;
        float d = 0.f;
        #pragma unroll
        for (int c8 = 0; c8 < 16; ++c8) {
            bf16x8 v = *(const bf16x8*)(xr + c8 * 8);
            #pragma unroll
            for (int j = 0; j < 8; ++j) d += b2f((u16)v[j]) * sgw[c8 * 8 + j];
        }
        sGv[tid] = 1.f / (1.f + __expf(-d));
    }
    f32x4 aout[2][8];
    f32x4 z = {0.f, 0.f, 0.f, 0.f};
    #pragma unroll
    for (int mf = 0; mf < 2; ++mf)
        #pragma unroll
        for (int nf = 0; nf < 8; ++nf) aout[mf][nf] = z;
    __syncthreads();                    // chunk0 resident; sGv visible
    for (int ic = 0; ic < 16; ++ic) {
        u16* cur = (ic & 1) ? sBufB : sBufA;
        u16* alt = (ic & 1) ? sBufA : sBufB;
        if (ic + 1 < 16)
            stage_img(alt, simg + (size_t)(ic + 1) * 13312, wid, lane);
        swiglu_chunk(cur, sH, av, aout, wid, g16, ln15);
        __syncthreads();
    }
    #pragma unroll
    for (int mf = 0; mf < 2; ++mf)
        #pragma unroll
        for (int nf = 0; nf < 8; ++nf)
            #pragma unroll
            for (int r = 0; r < 4; ++r) {
                int row = wid * 32 + mf * 16 + g16 * 4 + r;
                int col = nf * 16 + ln15;
                size_t t = (size_t)(tok0 + row);
                float fc = b2f(slotOut[(t * 2 + 0) * 128 + col])
                         + b2f(slotOut[(t * 2 + 1) * 128 + col]);
                size_t idx = t * 128 + col;
                outx[idx] = outx[idx] + fc + sGv[row] * aout[mf][nf][r];
            }
}

// ---------------- host launcher ----------------
// workspace layout (bytes)
#define SZTD  ((size_t)TOK * 128 * 2)          // 50331648, one bf16 [Tok,128] buffer
#define OFF_XN   ((size_t)0)                   // t_x_n (attn out)
#define OFF_KN   (SZTD)                        // mixed
#define OFF_Q    (SZTD * 2)                    // q -> t_xT -> x2n
#define OFF_KP   (SZTD * 3)                    // kp ; later slotOut bf16 [2*TOK][128] spans KP..KP+SZTD*2
#define OFF_VP   (SZTD * 4)                    // vp
#define OFF_ABF  (SZTD * 5)                    // a bf16 [2048,2048] = 8388608
#define OFF_LW   (OFF_ABF + 8388608)           // listw f32 [8*TOK]
#define OFF_LIST (OFF_LW + (size_t)8 * TOK * 4)
#define OFF_CNT  (OFF_LIST + (size_t)8 * TOK * 4)
#define OFF_ARENA (OFF_CNT + 128)              // bf16 arena: dense mats + chunk images

extern "C" void kernel_launch(void* const* d_in, const int* in_sizes, int n_in,
                              void* d_out, int out_size, void* d_ws, size_t ws_size,
                              hipStream_t stream) {
    (void)in_sizes; (void)n_in; (void)out_size; (void)ws_size;
    const float* x    = (const float*)d_in[0];
    const float* k    = (const float*)d_in[1];
    // d_in[2] (v) is unused by the reference
    const float* adj  = (const float*)d_in[3];
    const float* Wq   = (const float*)d_in[4];
    const float* bq   = (const float*)d_in[5];
    const float* Wk   = (const float*)d_in[6];
    const float* bk   = (const float*)d_in[7];
    const float* Wv   = (const float*)d_in[8];
    const float* bv   = (const float*)d_in[9];
    const float* ntw  = (const float*)d_in[10];
    const float* gfc1 = (const float*)d_in[11];
    const float* gmlp = (const float*)d_in[12];
    const float* gmlpb= (const float*)d_in[13];
    const float* n1w  = (const float*)d_in[14];
    const float* n2w  = (const float*)d_in[15];
    const float* gatew= (const float*)d_in[16];
    const float* ew1  = (const float*)d_in[17];
    const float* ew2  = (const float*)d_in[18];
    const float* ew3  = (const float*)d_in[19];
    const float* sw1  = (const float*)d_in[20];
    const float* sw2  = (const float*)d_in[21];
    const float* sw3  = (const float*)d_in[22];
    const float* sgw  = (const float*)d_in[23];

    char* ws = (char*)d_ws;
    u16*  xn   = (u16*)(ws + OFF_XN);
    u16*  kn   = (u16*)(ws + OFF_KN);
    u16*  qb   = (u16*)(ws + OFF_Q);
    u16*  kpb  = (u16*)(ws + OFF_KP);
    u16*  vpb  = (u16*)(ws + OFF_VP);
    u16*  slotOut = (u16*)(ws + OFF_KP);      // overlaps kp+vp (dead after attention)
    u16*  abf  = (u16*)(ws + OFF_ABF);
    float* lw  = (float*)(ws + OFF_LW);
    int*  lst  = (int*)(ws + OFF_LIST);
    int*  cnts = (int*)(ws + OFF_CNT);
    u16*  arena = (u16*)(ws + OFF_ARENA);
    u16*  bWq = arena;
    u16*  bWk = arena + 16384;
    u16*  bWv = arena + 32768;
    u16*  bG1 = arena + 49152;
    u16*  bG2 = arena + 65536;
    u16*  eimg = arena + 81920;               // 64 expert chunk images x 13312
    u16*  simg = arena + 933888;              // 16 shared chunk images x 13312
    float* outx   = (float*)d_out;
    float* outlog = outx + (size_t)TOK * 128;

    preconvert<<<600, 256, 0, stream>>>(Wq, Wk, Wv, gfc1, gmlp, ew1, ew2, ew3,
                                        sw1, sw2, sw3, arena, cnts);
    proj_rms<<<1536, 256, 0, stream>>>(x, bWq, bq, n1w, qb);
    projkv_rms<<<1536, 256, 0, stream>>>(k, bWk, bk, bWv, bv, n1w, kpb, vpb);
    attn_kernel<<<8192, 256, 0, stream>>>(qb, kpb, vpb, ntw, xn /* t_x_n */);
    adj_norm<<<2048, 256, 0, stream>>>(adj, abf);
    transpose_k<<<3072, 256, 0, stream>>>(xn, qb /* t_xT */);
    gcn_gemm<<<1536, 256, 0, stream>>>(abf, qb, kn /* mixed */);
    fused_gcn_router<<<1536, 256, 0, stream>>>(kn, xn, x, bG1, bG2, gmlpb, n2w, gatew,
                                               outx, outlog, qb /* x2n */, lst, lw, cnts);
    moe_expert<<<dim3(1536, 8), 256, 0, stream>>>(qb, lst, lw, cnts, eimg, slotOut);
    moe_shared<<<1536, 256, 0, stream>>>(qb, simg, sgw, slotOut, outx);
}